// Round 4
// baseline (384.192 us; speedup 1.0000x reference)
//
#include <hip/hip_runtime.h>
#include <hip/hip_bf16.h>

#define HIDDEN 896
#define HEADS 7
#define HDIM 128
#define BB 4
#define TT 2048
#define MTOT (BB*TT)   // 8192

// attn LDS strides (shorts): odd word-strides (65/33/33 words) -> bank stride odd
// -> max 2-way aliasing (free per m136). Total 50,432 B -> 3 blocks/CU.
#define KSP 130
#define VSP 66
#define PSP 66

typedef short bf16x8 __attribute__((ext_vector_type(8)));
typedef float f32x4 __attribute__((ext_vector_type(4)));

__device__ __forceinline__ short f2bf(float f) {
    union { float f; unsigned u; } v; v.f = f;
    unsigned r = (v.u + 0x7FFF + ((v.u >> 16) & 1)) >> 16;
    return (short)r;
}

// async global->LDS, 16B per lane; lds dst must be wave-uniform base (+lane*16 implicit)
__device__ __forceinline__ void gll16(const short* g, short* l) {
    __builtin_amdgcn_global_load_lds(
        (const __attribute__((address_space(1))) unsigned int*)g,
        (__attribute__((address_space(3))) unsigned int*)l, 16, 0, 0);
}

// ---------------- kernel 1: fused prep (cast x, cast Wo, transpose-cast Wq/Wk/Wv) ----
// role by blockIdx.x range: [0,7168) cast_x, [7168,7952) cast_wo, [7952,10304) transpose.
#define NB_CASTX (MTOT * HIDDEN / 1024)      // 7168
#define NB_CASTWO (HIDDEN * HIDDEN / 1024)   // 784
#define NB_TRANS (28 * 4 * 21)               // 2352
__global__ __launch_bounds__(256) void prep_fused(
    const float* __restrict__ x, const float* __restrict__ Wo,
    const float* __restrict__ Wq, const float* __restrict__ Wk,
    const float* __restrict__ Wv,
    short* __restrict__ xb, short* __restrict__ Wob, short* __restrict__ Wt)
{
    __shared__ float tile[32][33];
    const int bid = blockIdx.x;
    if (bid < NB_CASTX) {
        int base = (bid * 256 + threadIdx.x) * 4;
        float4 v = *(const float4*)(x + base);
        short4 o;
        o.x = f2bf(v.x); o.y = f2bf(v.y); o.z = f2bf(v.z); o.w = f2bf(v.w);
        *(short4*)(xb + base) = o;
    } else if (bid < NB_CASTX + NB_CASTWO) {
        int base = ((bid - NB_CASTX) * 256 + threadIdx.x) * 4;
        float4 v = *(const float4*)(Wo + base);
        short4 o;
        o.x = f2bf(v.x); o.y = f2bf(v.y); o.z = f2bf(v.z); o.w = f2bf(v.w);
        *(short4*)(Wob + base) = o;
    } else {
        int t = bid - NB_CASTX - NB_CASTWO;
        const int z = t / 112;               // 0..20
        const int rem = t % 112;
        const int bx = rem % 28, by = rem / 28;
        const int type = z / 7, head = z % 7;
        const float* src = (type == 0 ? Wq : (type == 1 ? Wk : Wv)) + head * (HIDDEN * HDIM);
        short* dst = Wt + (size_t)z * (HDIM * HIDDEN);
        const int r0 = bx * 32, c0 = by * 32;
        const int tx = threadIdx.x & 31, ty = threadIdx.x >> 5;  // 32 x 8
        for (int i = 0; i < 4; i++)
            tile[ty * 4 + i][tx] = src[(r0 + ty * 4 + i) * HDIM + c0 + tx];
        __syncthreads();
        for (int i = 0; i < 4; i++)
            dst[(c0 + ty * 4 + i) * HIDDEN + r0 + tx] = f2bf(tile[tx][ty * 4 + i]);
    }
}

// ---------------- kernel 2: QKV projection GEMM ----------------
// 128x128 tile, BK=64 as 2 x BK=32 sub-tiles per barrier pair: 14 outer iters
// (was 28), half the vmcnt(0)+lgkmcnt(0) barrier drains. Stride-32 sub-tile layout
// keeps ds_read_b128 at the 8-group floor rate (no swizzle needed). LDS 32 KB.
__global__ __launch_bounds__(256) void qkv_gemm(
    const short* __restrict__ xb, const short* __restrict__ Wt,
    short* __restrict__ Q, short* __restrict__ Kk, short* __restrict__ Vt)
{
    __shared__ short Ash[2][128 * 32];
    __shared__ short Bsh[2][128 * 32];
    const int z = blockIdx.x;
    const int m0 = blockIdx.y * 128;
    const int head = z % 7, type = z / 7;
    const short* Wz = Wt + (size_t)z * (HDIM * HIDDEN);

    const int tid = threadIdx.x;
    const int wave = tid >> 6, lane = tid & 63;
    const int quad = lane >> 4, l16 = lane & 15;
    const int wm = (wave >> 1) * 64, wn = (wave & 1) * 64;

    f32x4 acc[4][4] = {};

    const int r0 = tid >> 2, cc0 = (tid & 3) * 8;
    const int r1 = r0 + 64;
    const short* asrc0 = xb + (size_t)(m0 + r0) * HIDDEN + cc0;
    const short* asrc1 = xb + (size_t)(m0 + r1) * HIDDEN + cc0;
    const short* bsrc0 = Wz + (size_t)r0 * HIDDEN + cc0;
    const short* bsrc1 = Wz + (size_t)r1 * HIDDEN + cc0;

    for (int k0 = 0; k0 < HIDDEN; k0 += 64) {
        __syncthreads();                 // prev tiles fully consumed
        for (int s = 0; s < 2; s++) {
            gll16(asrc0 + k0 + s * 32, &Ash[s][wave * 512]);
            gll16(asrc1 + k0 + s * 32, &Ash[s][2048 + wave * 512]);
            gll16(bsrc0 + k0 + s * 32, &Bsh[s][wave * 512]);
            gll16(bsrc1 + k0 + s * 32, &Bsh[s][2048 + wave * 512]);
        }
        __syncthreads();                 // drains vmcnt -> both sub-tiles ready
        for (int s = 0; s < 2; s++) {
            bf16x8 af[4], bfr[4];
            for (int mi = 0; mi < 4; mi++)
                af[mi] = *(const bf16x8*)(&Ash[s][(wm + mi * 16 + l16) * 32 + quad * 8]);
            for (int ni = 0; ni < 4; ni++)
                bfr[ni] = *(const bf16x8*)(&Bsh[s][(wn + ni * 16 + l16) * 32 + quad * 8]);
            for (int mi = 0; mi < 4; mi++)
                for (int ni = 0; ni < 4; ni++)
                    acc[mi][ni] = __builtin_amdgcn_mfma_f32_16x16x32_bf16(af[mi], bfr[ni], acc[mi][ni], 0, 0, 0);
        }
    }

    const size_t base = (size_t)head * (MTOT * HDIM);
    if (type == 0) {
        // fold softmax scale AND log2(e) into Q (softmax done in exp2 domain)
        const float qs = 0.08838834764831845f * 1.4426950408889634f;
        for (int mi = 0; mi < 4; mi++)
            for (int ni = 0; ni < 4; ni++)
                for (int r = 0; r < 4; r++) {
                    int m = m0 + wm + mi * 16 + quad * 4 + r;
                    int n = wn + ni * 16 + l16;
                    Q[base + (size_t)m * HDIM + n] = f2bf(acc[mi][ni][r] * qs);
                }
    } else if (type == 1) {
        for (int mi = 0; mi < 4; mi++)
            for (int ni = 0; ni < 4; ni++)
                for (int r = 0; r < 4; r++) {
                    int m = m0 + wm + mi * 16 + quad * 4 + r;
                    int n = wn + ni * 16 + l16;
                    Kk[base + (size_t)m * HDIM + n] = f2bf(acc[mi][ni][r]);
                }
    } else {
        for (int mi = 0; mi < 4; mi++)
            for (int ni = 0; ni < 4; ni++) {
                int m = m0 + wm + mi * 16 + quad * 4;
                int bb = m >> 11, t = m & 2047;
                int n = wn + ni * 16 + l16;
                short4 o;
                o.x = f2bf(acc[mi][ni][0]); o.y = f2bf(acc[mi][ni][1]);
                o.z = f2bf(acc[mi][ni][2]); o.w = f2bf(acc[mi][ni][3]);
                *(short4*)(Vt + base + (size_t)bb * (HDIM * TT) + (size_t)n * TT + t) = o;
            }
    }
}

// ---------------- kernel 3: fano flash attention v12 ----------------
// Round-0 proven structure (staging + register prefetch + qt-reversal), with
// odd-word LDS strides (130/66/66 -> <=2-way bank aliasing, 50.4 KB -> 3 blocks/CU).
__global__ __launch_bounds__(256) void fano_attn(
    const short* __restrict__ Q, const short* __restrict__ K, const short* __restrict__ Vt,
    short* __restrict__ Ocat, const int* __restrict__ iscp)
{
    __shared__ short Ks[64 * KSP];
    __shared__ short Vs[128 * VSP];
    __shared__ short Ps[4][32 * PSP];

    const int causal = *iscp;
    const int mlin = blockIdx.y + 4 * blockIdx.z;   // b + 4h in [0,28)
    const int qt = (causal && mlin >= 16) ? ((int)gridDim.x - 1 - blockIdx.x)
                                          : (int)blockIdx.x;
    const int q0 = qt * 128;
    const int b = blockIdx.y, h = blockIdx.z;
    const int tid = threadIdx.x, wave = tid >> 6, lane = tid & 63;
    const int quad = lane >> 4, l16 = lane & 15;
    const int iw = q0 + wave * 32;   // wave's min q-row

    const short* Qb = Q + (size_t)(h * MTOT + b * TT + q0) * HDIM;
    const short* Kb = K + (size_t)(h * MTOT + b * TT) * HDIM;
    const short* Vb = Vt + (size_t)h * MTOT * HDIM + (size_t)b * HDIM * TT;

    bf16x8 qf[2][4];
    for (int g = 0; g < 2; g++)
        for (int ks = 0; ks < 4; ks++)
            qf[g][ks] = *(const bf16x8*)(Qb + (size_t)(wave * 32 + g * 16 + l16) * HDIM + ks * 32 + quad * 8);

    f32x4 oacc[2][8] = {};
    f32x4 lacc[2] = {};
    int irow[2][4];
    for (int g = 0; g < 2; g++)
        for (int r = 0; r < 4; r++)
            irow[g][r] = q0 + wave * 32 + g * 16 + quad * 4 + r;

    const bf16x8 vones = {0x3F80, 0x3F80, 0x3F80, 0x3F80, 0x3F80, 0x3F80, 0x3F80, 0x3F80};

    int krow[4], kcol[4], vrow[4], vcol[4];
    for (int i = 0; i < 4; i++) {
        int c = tid + i * 256;
        krow[i] = c >> 4; kcol[i] = (c & 15) * 8;
        vrow[i] = c >> 3; vcol[i] = (c & 7) * 8;
    }

    const int send = causal ? (q0 + 128) : TT;

    bf16x8 kreg[4], vreg[4];
    for (int i = 0; i < 4; i++) {
        kreg[i] = *(const bf16x8*)(Kb + (size_t)krow[i] * HDIM + kcol[i]);
        vreg[i] = *(const bf16x8*)(Vb + (size_t)vrow[i] * TT + vcol[i]);
    }

    int d7b = (l16 - h + 7) % 7;
    short* Pw = &Ps[wave][0];

    for (int s0 = 0; s0 < send; s0 += 64) {
        __syncthreads();
        for (int i = 0; i < 4; i++) {
            *(bf16x8*)(Ks + krow[i] * KSP + kcol[i]) = kreg[i];
            *(bf16x8*)(Vs + vrow[i] * VSP + vcol[i]) = vreg[i];
        }
        __syncthreads();

        int sn = s0 + 64; if (sn >= send) sn = s0;
        const short* Kn = Kb + (size_t)sn * HDIM;
        const short* Vn = Vb + sn;
        for (int i = 0; i < 4; i++) {
            kreg[i] = *(const bf16x8*)(Kn + (size_t)krow[i] * HDIM + kcol[i]);
            vreg[i] = *(const bf16x8*)(Vn + (size_t)vrow[i] * TT + vcol[i]);
        }

        f32x4 sacc[2][4] = {};
        for (int ni = 0; ni < 4; ni++)
            for (int ks = 0; ks < 4; ks++) {
                bf16x8 bk = *(const bf16x8*)(Ks + (ni * 16 + l16) * KSP + ks * 32 + quad * 8);
                sacc[0][ni] = __builtin_amdgcn_mfma_f32_16x16x32_bf16(qf[0][ks], bk, sacc[0][ni], 0, 0, 0);
                sacc[1][ni] = __builtin_amdgcn_mfma_f32_16x16x32_bf16(qf[1][ks], bk, sacc[1][ni], 0, 0, 0);
            }

        const bool full = (s0 + 80 > iw) && (causal || (s0 < iw + 48));
        if (full) {
            for (int ni = 0; ni < 4; ni++) {
                int d7 = d7b + 2 * ni; if (d7 >= 7) d7 -= 7;
                bool line = (0x0B >> d7) & 1;
                int s = s0 + ni * 16 + l16;
                for (int g = 0; g < 2; g++)
                    for (int r = 0; r < 4; r++) {
                        int i = irow[g][r];
                        bool ok = causal ? ((s <= i) & (line | (s >= i - 16)))
                                         : (line | ((s >= i - 16) & (s <= i + 16)));
                        sacc[g][ni][r] = ok ? exp2f(sacc[g][ni][r]) : 0.0f;
                    }
            }
        } else {
            for (int ni = 0; ni < 4; ni++) {
                int d7 = d7b + 2 * ni; if (d7 >= 7) d7 -= 7;
                bool line = (0x0B >> d7) & 1;
                for (int g = 0; g < 2; g++)
                    for (int r = 0; r < 4; r++)
                        sacc[g][ni][r] = line ? exp2f(sacc[g][ni][r]) : 0.0f;
            }
        }
        d7b++; if (d7b == 7) d7b = 0;

        for (int g = 0; g < 2; g++)
            for (int ni = 0; ni < 4; ni++)
                for (int r = 0; r < 4; r++)
                    Pw[(g * 16 + quad * 4 + r) * PSP + ni * 16 + l16] = f2bf(sacc[g][ni][r]);

        for (int ks2 = 0; ks2 < 2; ks2++) {
            bf16x8 ap0 = *(const bf16x8*)(Pw + l16 * PSP + ks2 * 32 + quad * 8);
            bf16x8 ap1 = *(const bf16x8*)(Pw + (16 + l16) * PSP + ks2 * 32 + quad * 8);
            lacc[0] = __builtin_amdgcn_mfma_f32_16x16x32_bf16(ap0, vones, lacc[0], 0, 0, 0);
            lacc[1] = __builtin_amdgcn_mfma_f32_16x16x32_bf16(ap1, vones, lacc[1], 0, 0, 0);
            for (int nj = 0; nj < 8; nj++) {
                bf16x8 bv = *(const bf16x8*)(Vs + (nj * 16 + l16) * VSP + ks2 * 32 + quad * 8);
                oacc[0][nj] = __builtin_amdgcn_mfma_f32_16x16x32_bf16(ap0, bv, oacc[0][nj], 0, 0, 0);
                oacc[1][nj] = __builtin_amdgcn_mfma_f32_16x16x32_bf16(ap1, bv, oacc[1][nj], 0, 0, 0);
            }
        }
    }

    short* Obase = Ocat + (size_t)(b * TT) * HIDDEN + h * HDIM;
    for (int g = 0; g < 2; g++) {
        float inv[4];
        for (int r = 0; r < 4; r++) inv[r] = 1.0f / lacc[g][r];
        for (int nj = 0; nj < 8; nj++)
            for (int r = 0; r < 4; r++)
                Obase[(size_t)irow[g][r] * HIDDEN + nj * 16 + l16] = f2bf(oacc[g][nj][r] * inv[r]);
    }
}

// ---------------- kernel 4: output projection ----------------
// 128x128 tile, 2 x BK=32 sub-tiles per barrier pair (14 outer iters).
// grid (7 n, 64 m): consecutive blocks share the A tile (L2-hot).
__global__ __launch_bounds__(256) void out_gemm(
    const short* __restrict__ A, const short* __restrict__ Bt, float* __restrict__ out)
{
    __shared__ short Ash[2][128 * 32];
    __shared__ short Bsh[2][128 * 32];
    const int n0 = blockIdx.x * 128;
    const int m0 = blockIdx.y * 128;

    const int tid = threadIdx.x;
    const int wave = tid >> 6, lane = tid & 63;
    const int quad = lane >> 4, l16 = lane & 15;
    const int wm = (wave >> 1) * 64, wn = (wave & 1) * 64;

    f32x4 acc[4][4] = {};

    const int r0 = tid >> 2, cc0 = (tid & 3) * 8;
    const int r1 = r0 + 64;
    const short* asrc0 = A + (size_t)(m0 + r0) * HIDDEN + cc0;
    const short* asrc1 = A + (size_t)(m0 + r1) * HIDDEN + cc0;
    const short* bsrc0 = Bt + (size_t)(n0 + r0) * HIDDEN + cc0;
    const short* bsrc1 = Bt + (size_t)(n0 + r1) * HIDDEN + cc0;

    for (int k0 = 0; k0 < HIDDEN; k0 += 64) {
        __syncthreads();
        for (int s = 0; s < 2; s++) {
            gll16(asrc0 + k0 + s * 32, &Ash[s][wave * 512]);
            gll16(asrc1 + k0 + s * 32, &Ash[s][2048 + wave * 512]);
            gll16(bsrc0 + k0 + s * 32, &Bsh[s][wave * 512]);
            gll16(bsrc1 + k0 + s * 32, &Bsh[s][2048 + wave * 512]);
        }
        __syncthreads();
        for (int s = 0; s < 2; s++) {
            bf16x8 af[4], bfr[4];
            for (int mi = 0; mi < 4; mi++)
                af[mi] = *(const bf16x8*)(&Ash[s][(wm + mi * 16 + l16) * 32 + quad * 8]);
            for (int ni = 0; ni < 4; ni++)
                bfr[ni] = *(const bf16x8*)(&Bsh[s][(wn + ni * 16 + l16) * 32 + quad * 8]);
            for (int mi = 0; mi < 4; mi++)
                for (int ni = 0; ni < 4; ni++)
                    acc[mi][ni] = __builtin_amdgcn_mfma_f32_16x16x32_bf16(af[mi], bfr[ni], acc[mi][ni], 0, 0, 0);
        }
    }

    for (int mi = 0; mi < 4; mi++)
        for (int ni = 0; ni < 4; ni++)
            for (int r = 0; r < 4; r++) {
                int m = m0 + wm + mi * 16 + quad * 4 + r;
                int n = n0 + wn + ni * 16 + l16;
                out[(size_t)m * HIDDEN + n] = acc[mi][ni][r];
            }
}

extern "C" void kernel_launch(void* const* d_in, const int* in_sizes, int n_in,
                              void* d_out, int out_size, void* d_ws, size_t ws_size,
                              hipStream_t stream) {
    (void)in_sizes; (void)n_in; (void)out_size; (void)ws_size;
    const float* x  = (const float*)d_in[0];
    const float* Wq = (const float*)d_in[1];
    const float* Wk = (const float*)d_in[2];
    const float* Wv = (const float*)d_in[3];
    const float* Wo = (const float*)d_in[4];
    const int* iscp = (const int*)d_in[5];
    float* out = (float*)d_out;

    short* xb   = (short*)d_ws;                       // 8192*896
    short* Qb   = xb   + (size_t)MTOT * HIDDEN;       // 7*8192*128 each
    short* Kb   = Qb   + (size_t)HEADS * MTOT * HDIM;
    short* Vtb  = Kb   + (size_t)HEADS * MTOT * HDIM;
    short* Ocat = Vtb  + (size_t)HEADS * MTOT * HDIM; // 8192*896 (aliased with Wt)
    short* Wt   = Ocat;                               // 21*128*896, used only before attn
    short* Wob  = Ocat + (size_t)MTOT * HIDDEN;       // 896*896

    prep_fused<<<NB_CASTX + NB_CASTWO + NB_TRANS, 256, 0, stream>>>(
        x, Wo, Wq, Wk, Wv, xb, Wob, Wt);
    qkv_gemm<<<dim3(21, MTOT / 128), 256, 0, stream>>>(xb, Wt, Qb, Kb, Vtb);
    fano_attn<<<dim3(TT / 128, BB, HEADS), 256, 0, stream>>>(Qb, Kb, Vtb, Ocat, iscp);
    out_gemm<<<dim3(HIDDEN / 128, MTOT / 128), 256, 0, stream>>>(Ocat, Wob, out);
}

// Round 5
// 321.288 us; speedup vs baseline: 1.1958x; 1.1958x over previous
//
#include <hip/hip_runtime.h>
#include <hip/hip_bf16.h>

#define HIDDEN 896
#define HEADS 7
#define HDIM 128
#define BB 4
#define TT 2048
#define MTOT (BB*TT)   // 8192

// attn LDS strides (shorts). 132/68/68 (66/34/34 words) measured best: round-3 build
// had 975K conflicts vs 4.39M (136/72) and 10.7M (130/66). Total 51,712 B.
#define KSP 132
#define VSP 68
#define PSP 68

#define SCP 896        // compacted line-column buffer: padded length (>= 879, mult of 64)

typedef short bf16x8 __attribute__((ext_vector_type(8)));
typedef float f32x4 __attribute__((ext_vector_type(4)));

__device__ __forceinline__ short f2bf(float f) {
    union { float f; unsigned u; } v; v.f = f;
    unsigned r = (v.u + 0x7FFF + ((v.u >> 16) & 1)) >> 16;
    return (short)r;
}

// async global->LDS, 16B per lane; lds dst must be wave-uniform base (+lane*16 implicit)
__device__ __forceinline__ void gll16(const short* g, short* l) {
    __builtin_amdgcn_global_load_lds(
        (const __attribute__((address_space(1))) unsigned int*)g,
        (__attribute__((address_space(3))) unsigned int*)l, 16, 0, 0);
}

// line membership: head h attends column s iff bit (s%7) of m_h set, m_h = {h,h+1,h+3} mod 7
__device__ __forceinline__ unsigned linemask(int h) {
    return ((0x0Bu << h) | (0x0Bu >> (7 - h))) & 0x7Fu;
}
// number of line columns with s < X  (X >= 0)
__device__ __forceinline__ int linecnt(unsigned m, int X) {
    return (X / 7) * 3 + __popc(m & ((1u << (X % 7)) - 1u));
}

// ---------------- kernel 1: fused prep (cast x, cast Wo, transpose-cast Wq/Wk/Wv) ----
#define NB_CASTX (MTOT * HIDDEN / 1024)      // 7168
#define NB_CASTWO (HIDDEN * HIDDEN / 1024)   // 784
#define NB_TRANS (28 * 4 * 21)               // 2352
__global__ __launch_bounds__(256) void prep_fused(
    const float* __restrict__ x, const float* __restrict__ Wo,
    const float* __restrict__ Wq, const float* __restrict__ Wk,
    const float* __restrict__ Wv,
    short* __restrict__ xb, short* __restrict__ Wob, short* __restrict__ Wt)
{
    __shared__ float tile[32][33];
    const int bid = blockIdx.x;
    if (bid < NB_CASTX) {
        int base = (bid * 256 + threadIdx.x) * 4;
        float4 v = *(const float4*)(x + base);
        short4 o;
        o.x = f2bf(v.x); o.y = f2bf(v.y); o.z = f2bf(v.z); o.w = f2bf(v.w);
        *(short4*)(xb + base) = o;
    } else if (bid < NB_CASTX + NB_CASTWO) {
        int base = ((bid - NB_CASTX) * 256 + threadIdx.x) * 4;
        float4 v = *(const float4*)(Wo + base);
        short4 o;
        o.x = f2bf(v.x); o.y = f2bf(v.y); o.z = f2bf(v.z); o.w = f2bf(v.w);
        *(short4*)(Wob + base) = o;
    } else {
        int t = bid - NB_CASTX - NB_CASTWO;
        const int z = t / 112;               // 0..20
        const int rem = t % 112;
        const int bx = rem % 28, by = rem / 28;
        const int type = z / 7, head = z % 7;
        const float* src = (type == 0 ? Wq : (type == 1 ? Wk : Wv)) + head * (HIDDEN * HDIM);
        short* dst = Wt + (size_t)z * (HDIM * HIDDEN);
        const int r0 = bx * 32, c0 = by * 32;
        const int tx = threadIdx.x & 31, ty = threadIdx.x >> 5;  // 32 x 8
        for (int i = 0; i < 4; i++)
            tile[ty * 4 + i][tx] = src[(r0 + ty * 4 + i) * HDIM + c0 + tx];
        __syncthreads();
        for (int i = 0; i < 4; i++)
            dst[(c0 + ty * 4 + i) * HIDDEN + r0 + tx] = f2bf(tile[tx][ty * 4 + i]);
    }
}

// ---------------- kernel 2: QKV projection GEMM (2 x BK=32 sub-tiles per barrier) ----
__global__ __launch_bounds__(256) void qkv_gemm(
    const short* __restrict__ xb, const short* __restrict__ Wt,
    short* __restrict__ Q, short* __restrict__ Kk, short* __restrict__ Vt)
{
    __shared__ short Ash[2][128 * 32];
    __shared__ short Bsh[2][128 * 32];
    const int z = blockIdx.x;
    const int m0 = blockIdx.y * 128;
    const int head = z % 7, type = z / 7;
    const short* Wz = Wt + (size_t)z * (HDIM * HIDDEN);

    const int tid = threadIdx.x;
    const int wave = tid >> 6, lane = tid & 63;
    const int quad = lane >> 4, l16 = lane & 15;
    const int wm = (wave >> 1) * 64, wn = (wave & 1) * 64;

    f32x4 acc[4][4] = {};

    const int r0 = tid >> 2, cc0 = (tid & 3) * 8;
    const int r1 = r0 + 64;
    const short* asrc0 = xb + (size_t)(m0 + r0) * HIDDEN + cc0;
    const short* asrc1 = xb + (size_t)(m0 + r1) * HIDDEN + cc0;
    const short* bsrc0 = Wz + (size_t)r0 * HIDDEN + cc0;
    const short* bsrc1 = Wz + (size_t)r1 * HIDDEN + cc0;

    for (int k0 = 0; k0 < HIDDEN; k0 += 64) {
        __syncthreads();
        for (int s = 0; s < 2; s++) {
            gll16(asrc0 + k0 + s * 32, &Ash[s][wave * 512]);
            gll16(asrc1 + k0 + s * 32, &Ash[s][2048 + wave * 512]);
            gll16(bsrc0 + k0 + s * 32, &Bsh[s][wave * 512]);
            gll16(bsrc1 + k0 + s * 32, &Bsh[s][2048 + wave * 512]);
        }
        __syncthreads();
        for (int s = 0; s < 2; s++) {
            bf16x8 af[4], bfr[4];
            for (int mi = 0; mi < 4; mi++)
                af[mi] = *(const bf16x8*)(&Ash[s][(wm + mi * 16 + l16) * 32 + quad * 8]);
            for (int ni = 0; ni < 4; ni++)
                bfr[ni] = *(const bf16x8*)(&Bsh[s][(wn + ni * 16 + l16) * 32 + quad * 8]);
            for (int mi = 0; mi < 4; mi++)
                for (int ni = 0; ni < 4; ni++)
                    acc[mi][ni] = __builtin_amdgcn_mfma_f32_16x16x32_bf16(af[mi], bfr[ni], acc[mi][ni], 0, 0, 0);
        }
    }

    const size_t base = (size_t)head * (MTOT * HDIM);
    if (type == 0) {
        const float qs = 0.08838834764831845f * 1.4426950408889634f;
        for (int mi = 0; mi < 4; mi++)
            for (int ni = 0; ni < 4; ni++)
                for (int r = 0; r < 4; r++) {
                    int m = m0 + wm + mi * 16 + quad * 4 + r;
                    int n = wn + ni * 16 + l16;
                    Q[base + (size_t)m * HDIM + n] = f2bf(acc[mi][ni][r] * qs);
                }
    } else if (type == 1) {
        for (int mi = 0; mi < 4; mi++)
            for (int ni = 0; ni < 4; ni++)
                for (int r = 0; r < 4; r++) {
                    int m = m0 + wm + mi * 16 + quad * 4 + r;
                    int n = wn + ni * 16 + l16;
                    Kk[base + (size_t)m * HDIM + n] = f2bf(acc[mi][ni][r]);
                }
    } else {
        for (int mi = 0; mi < 4; mi++)
            for (int ni = 0; ni < 4; ni++) {
                int m = m0 + wm + mi * 16 + quad * 4;
                int bb = m >> 11, t = m & 2047;
                int n = wn + ni * 16 + l16;
                short4 o;
                o.x = f2bf(acc[mi][ni][0]); o.y = f2bf(acc[mi][ni][1]);
                o.z = f2bf(acc[mi][ni][2]); o.w = f2bf(acc[mi][ni][3]);
                *(short4*)(Vt + base + (size_t)bb * (HDIM * TT) + (size_t)n * TT + t) = o;
            }
    }
}

// ---------------- kernel 2.5a: compact K to line-columns (ascending s) ----------------
// Kc[hb][s'][d], s' < c_tot maps to the s'-th line column; rows [c_tot,896) zeroed.
__global__ __launch_bounds__(256) void compact_k(const short* __restrict__ K,
                                                 short* __restrict__ Kc)
{
    const int hb = blockIdx.x, h = hb >> 2, b = hb & 3;
    const unsigned m = linemask(h);
    const int c_tot = 876 + __popc(m & 0xFu);
    const int o0 = __ffs(m) - 1;
    const unsigned m1 = m & (m - 1);
    const int o1 = __ffs(m1) - 1;
    const unsigned m2 = m1 & (m1 - 1);
    const int o2 = __ffs(m2) - 1;
    const int r = blockIdx.y * 32 + (threadIdx.x >> 3);
    const int c = (threadIdx.x & 7) * 16;
    short* dst = Kc + ((size_t)hb * SCP + r) * HDIM + c;
    if (r < c_tot) {
        int g = r / 3, id = r - g * 3;
        int s = g * 7 + (id == 0 ? o0 : (id == 1 ? o1 : o2));
        const short* src = K + (size_t)(h * MTOT + b * TT + s) * HDIM + c;
        *(bf16x8*)dst = *(const bf16x8*)src;
        *(bf16x8*)(dst + 8) = *(const bf16x8*)(src + 8);
    } else {
        bf16x8 z = {};
        *(bf16x8*)dst = z;
        *(bf16x8*)(dst + 8) = z;
    }
}

// ---------------- kernel 2.5b: compact V^T to line-columns ----------------
// Vc[hb][d][s'] (stride SCP); cols [c_tot,896) zeroed (avoid NaN contamination in PV).
__global__ __launch_bounds__(256) void compact_v(const short* __restrict__ Vt,
                                                 short* __restrict__ Vc)
{
    const int hb = blockIdx.x, h = hb >> 2, b = hb & 3;
    const int d = blockIdx.y;
    const unsigned m = linemask(h);
    const int c_tot = 876 + __popc(m & 0xFu);
    const int o0 = __ffs(m) - 1;
    const unsigned m1 = m & (m - 1);
    const int o1 = __ffs(m1) - 1;
    const unsigned m2 = m1 & (m1 - 1);
    const int o2 = __ffs(m2) - 1;
    const short* src = Vt + (size_t)h * MTOT * HDIM + (size_t)b * HDIM * TT + (size_t)d * TT;
    short* dst = Vc + ((size_t)hb * HDIM + d) * SCP;
    for (int sp = threadIdx.x * 4; sp < SCP; sp += 1024) {
        short4 o;
        short* po = (short*)&o;
        for (int j = 0; j < 4; j++) {
            int spp = sp + j;
            short v = 0;
            if (spp < c_tot) {
                int g = spp / 3, id = spp - g * 3;
                int s = g * 7 + (id == 0 ? o0 : (id == 1 ? o1 : o2));
                v = src[s];
            }
            po[j] = v;
        }
        *(short4*)(dst + sp) = o;
    }
}

// ---------------- kernel 3: fano flash attention v13 (line-compacted far phase) -------
// Phases per block:
//   A: compacted line columns s < sB0 (= q0-64): causal & window auto-satisfied -> no
//      per-element fano/causal mask, only a column-bound compare. 3/7 the tiles.
//   B: uncompacted [sB0, sB1) with the proven full-mask path (3 tiles causal).
//   C (non-causal only): compacted line columns s >= sB1.
__global__ __launch_bounds__(256) void fano_attn(
    const short* __restrict__ Q, const short* __restrict__ K, const short* __restrict__ Vt,
    const short* __restrict__ Kc, const short* __restrict__ Vc,
    short* __restrict__ Ocat, const int* __restrict__ iscp)
{
    __shared__ short Ks[64 * KSP];
    __shared__ short Vs[128 * VSP];
    __shared__ short Ps[4][32 * PSP];

    const int causal = *iscp;
    const int mlin = blockIdx.y + 4 * blockIdx.z;   // b + 4h in [0,28)
    const int qt = (causal && mlin >= 16) ? ((int)gridDim.x - 1 - blockIdx.x)
                                          : (int)blockIdx.x;
    const int q0 = qt * 128;
    const int b = blockIdx.y, h = blockIdx.z;
    const int hb = h * 4 + b;
    const int tid = threadIdx.x, wave = tid >> 6, lane = tid & 63;
    const int quad = lane >> 4, l16 = lane & 15;
    const int iw = q0 + wave * 32;

    const short* Qb = Q + (size_t)(h * MTOT + b * TT + q0) * HDIM;
    const short* Kb = K + (size_t)(h * MTOT + b * TT) * HDIM;
    const short* Vb = Vt + (size_t)h * MTOT * HDIM + (size_t)b * HDIM * TT;
    const short* Kcb = Kc + (size_t)hb * SCP * HDIM;
    const short* Vcb = Vc + (size_t)hb * HDIM * SCP;

    bf16x8 qf[2][4];
    for (int g = 0; g < 2; g++)
        for (int ks = 0; ks < 4; ks++)
            qf[g][ks] = *(const bf16x8*)(Qb + (size_t)(wave * 32 + g * 16 + l16) * HDIM + ks * 32 + quad * 8);

    f32x4 oacc[2][8] = {};
    f32x4 lacc[2] = {};
    int irow[2][4];
    for (int g = 0; g < 2; g++)
        for (int r = 0; r < 4; r++)
            irow[g][r] = q0 + wave * 32 + g * 16 + quad * 4 + r;

    const bf16x8 vones = {0x3F80, 0x3F80, 0x3F80, 0x3F80, 0x3F80, 0x3F80, 0x3F80, 0x3F80};

    int krow[4], kcol[4], vrow[4], vcol[4];
    for (int i = 0; i < 4; i++) {
        int c = tid + i * 256;
        krow[i] = c >> 4; kcol[i] = (c & 15) * 8;
        vrow[i] = c >> 3; vcol[i] = (c & 7) * 8;
    }

    const unsigned m_h = linemask(h);
    const int c_tot = 876 + __popc(m_h & 0xFu);
    const int sB0 = (causal && q0 >= 64) ? (q0 - 64) : 0;
    const int sB1 = causal ? (q0 + 128) : (q0 + 192 < TT ? q0 + 192 : TT);
    const int cA = linecnt(m_h, sB0);
    const int cC0 = causal ? c_tot : linecnt(m_h, sB1);
    const int l16h = (l16 - h + 7) % 7;

    short* Pw = &Ps[wave][0];

    const int nph = causal ? 2 : 3;
    for (int p = 0; p < nph; p++) {
        const short *Kp, *Vp;
        int vstr, t0, t1, c0v = 0, c1v = 0;
        if (p == 0)      { Kp = Kcb; Vp = Vcb; vstr = SCP; t0 = 0;        t1 = (cA + 63) >> 6;    c0v = 0;   c1v = cA; }
        else if (p == 1) { Kp = Kb;  Vp = Vb;  vstr = TT;  t0 = sB0 >> 6; t1 = sB1 >> 6; }
        else             { Kp = Kcb; Vp = Vcb; vstr = SCP; t0 = cC0 >> 6; t1 = (c_tot + 63) >> 6; c0v = cC0; c1v = c_tot; }
        if (t0 >= t1) continue;
        const bool comp = (p != 1);
        int s0q = sB0 % 7;

        bf16x8 kreg[4], vreg[4];
        {
            const int si = t0 * 64;
            for (int i = 0; i < 4; i++) {
                kreg[i] = *(const bf16x8*)(Kp + (size_t)(si + krow[i]) * HDIM + kcol[i]);
                vreg[i] = *(const bf16x8*)(Vp + (size_t)vrow[i] * vstr + si + vcol[i]);
            }
        }

        for (int t = t0; t < t1; t++) {
            const int s0 = t * 64;
            __syncthreads();
            for (int i = 0; i < 4; i++) {
                *(bf16x8*)(Ks + krow[i] * KSP + kcol[i]) = kreg[i];
                *(bf16x8*)(Vs + vrow[i] * VSP + vcol[i]) = vreg[i];
            }
            __syncthreads();

            int tn = t + 1; if (tn >= t1) tn = t0;
            const int sn = tn * 64;
            for (int i = 0; i < 4; i++) {
                kreg[i] = *(const bf16x8*)(Kp + (size_t)(sn + krow[i]) * HDIM + kcol[i]);
                vreg[i] = *(const bf16x8*)(Vp + (size_t)vrow[i] * vstr + sn + vcol[i]);
            }

            f32x4 sacc[2][4] = {};
            for (int ni = 0; ni < 4; ni++)
                for (int ks = 0; ks < 4; ks++) {
                    bf16x8 bk = *(const bf16x8*)(Ks + (ni * 16 + l16) * KSP + ks * 32 + quad * 8);
                    sacc[0][ni] = __builtin_amdgcn_mfma_f32_16x16x32_bf16(qf[0][ks], bk, sacc[0][ni], 0, 0, 0);
                    sacc[1][ni] = __builtin_amdgcn_mfma_f32_16x16x32_bf16(qf[1][ks], bk, sacc[1][ni], 0, 0, 0);
                }

            if (comp) {
                // compacted phase: all columns are line-hits; only range-bound mask
                for (int ni = 0; ni < 4; ni++) {
                    int scol = s0 + ni * 16 + l16;
                    bool ok = (scol >= c0v) & (scol < c1v);
                    for (int g = 0; g < 2; g++)
                        for (int r = 0; r < 4; r++)
                            sacc[g][ni][r] = ok ? exp2f(sacc[g][ni][r]) : 0.0f;
                }
            } else {
                int d7b = l16h + s0q; if (d7b >= 7) d7b -= 7;
                for (int ni = 0; ni < 4; ni++) {
                    int d7 = d7b + 2 * ni; if (d7 >= 7) d7 -= 7;
                    bool line = (0x0B >> d7) & 1;
                    int s = s0 + ni * 16 + l16;
                    for (int g = 0; g < 2; g++)
                        for (int r = 0; r < 4; r++) {
                            int i = irow[g][r];
                            bool ok = causal ? ((s <= i) & (line | (s >= i - 16)))
                                             : (line | ((s >= i - 16) & (s <= i + 16)));
                            sacc[g][ni][r] = ok ? exp2f(sacc[g][ni][r]) : 0.0f;
                        }
                }
                s0q++; if (s0q == 7) s0q = 0;
            }

            for (int g = 0; g < 2; g++)
                for (int ni = 0; ni < 4; ni++)
                    for (int r = 0; r < 4; r++)
                        Pw[(g * 16 + quad * 4 + r) * PSP + ni * 16 + l16] = f2bf(sacc[g][ni][r]);

            for (int ks2 = 0; ks2 < 2; ks2++) {
                bf16x8 ap0 = *(const bf16x8*)(Pw + l16 * PSP + ks2 * 32 + quad * 8);
                bf16x8 ap1 = *(const bf16x8*)(Pw + (16 + l16) * PSP + ks2 * 32 + quad * 8);
                lacc[0] = __builtin_amdgcn_mfma_f32_16x16x32_bf16(ap0, vones, lacc[0], 0, 0, 0);
                lacc[1] = __builtin_amdgcn_mfma_f32_16x16x32_bf16(ap1, vones, lacc[1], 0, 0, 0);
                for (int nj = 0; nj < 8; nj++) {
                    bf16x8 bv = *(const bf16x8*)(Vs + (nj * 16 + l16) * VSP + ks2 * 32 + quad * 8);
                    oacc[0][nj] = __builtin_amdgcn_mfma_f32_16x16x32_bf16(ap0, bv, oacc[0][nj], 0, 0, 0);
                    oacc[1][nj] = __builtin_amdgcn_mfma_f32_16x16x32_bf16(ap1, bv, oacc[1][nj], 0, 0, 0);
                }
            }
        }
    }

    short* Obase = Ocat + (size_t)(b * TT) * HIDDEN + h * HDIM;
    for (int g = 0; g < 2; g++) {
        float inv[4];
        for (int r = 0; r < 4; r++) inv[r] = 1.0f / lacc[g][r];
        for (int nj = 0; nj < 8; nj++)
            for (int r = 0; r < 4; r++)
                Obase[(size_t)irow[g][r] * HIDDEN + nj * 16 + l16] = f2bf(oacc[g][nj][r] * inv[r]);
    }
}

// ---------------- kernel 4: output projection (2 x BK=32 sub-tiles per barrier) -------
__global__ __launch_bounds__(256) void out_gemm(
    const short* __restrict__ A, const short* __restrict__ Bt, float* __restrict__ out)
{
    __shared__ short Ash[2][128 * 32];
    __shared__ short Bsh[2][128 * 32];
    const int n0 = blockIdx.x * 128;
    const int m0 = blockIdx.y * 128;

    const int tid = threadIdx.x;
    const int wave = tid >> 6, lane = tid & 63;
    const int quad = lane >> 4, l16 = lane & 15;
    const int wm = (wave >> 1) * 64, wn = (wave & 1) * 64;

    f32x4 acc[4][4] = {};

    const int r0 = tid >> 2, cc0 = (tid & 3) * 8;
    const int r1 = r0 + 64;
    const short* asrc0 = A + (size_t)(m0 + r0) * HIDDEN + cc0;
    const short* asrc1 = A + (size_t)(m0 + r1) * HIDDEN + cc0;
    const short* bsrc0 = Bt + (size_t)(n0 + r0) * HIDDEN + cc0;
    const short* bsrc1 = Bt + (size_t)(n0 + r1) * HIDDEN + cc0;

    for (int k0 = 0; k0 < HIDDEN; k0 += 64) {
        __syncthreads();
        for (int s = 0; s < 2; s++) {
            gll16(asrc0 + k0 + s * 32, &Ash[s][wave * 512]);
            gll16(asrc1 + k0 + s * 32, &Ash[s][2048 + wave * 512]);
            gll16(bsrc0 + k0 + s * 32, &Bsh[s][wave * 512]);
            gll16(bsrc1 + k0 + s * 32, &Bsh[s][2048 + wave * 512]);
        }
        __syncthreads();
        for (int s = 0; s < 2; s++) {
            bf16x8 af[4], bfr[4];
            for (int mi = 0; mi < 4; mi++)
                af[mi] = *(const bf16x8*)(&Ash[s][(wm + mi * 16 + l16) * 32 + quad * 8]);
            for (int ni = 0; ni < 4; ni++)
                bfr[ni] = *(const bf16x8*)(&Bsh[s][(wn + ni * 16 + l16) * 32 + quad * 8]);
            for (int mi = 0; mi < 4; mi++)
                for (int ni = 0; ni < 4; ni++)
                    acc[mi][ni] = __builtin_amdgcn_mfma_f32_16x16x32_bf16(af[mi], bfr[ni], acc[mi][ni], 0, 0, 0);
        }
    }

    for (int mi = 0; mi < 4; mi++)
        for (int ni = 0; ni < 4; ni++)
            for (int r = 0; r < 4; r++) {
                int m = m0 + wm + mi * 16 + quad * 4 + r;
                int n = n0 + wn + ni * 16 + l16;
                out[(size_t)m * HIDDEN + n] = acc[mi][ni][r];
            }
}

extern "C" void kernel_launch(void* const* d_in, const int* in_sizes, int n_in,
                              void* d_out, int out_size, void* d_ws, size_t ws_size,
                              hipStream_t stream) {
    (void)in_sizes; (void)n_in; (void)out_size; (void)ws_size;
    const float* x  = (const float*)d_in[0];
    const float* Wq = (const float*)d_in[1];
    const float* Wk = (const float*)d_in[2];
    const float* Wv = (const float*)d_in[3];
    const float* Wo = (const float*)d_in[4];
    const int* iscp = (const int*)d_in[5];
    float* out = (float*)d_out;

    short* xb   = (short*)d_ws;                       // 8192*896 shorts = 14.68 MB
    short* Qb   = xb   + (size_t)MTOT * HIDDEN;       // 7*8192*128 each
    short* Kb   = Qb   + (size_t)HEADS * MTOT * HDIM;
    short* Vtb  = Kb   + (size_t)HEADS * MTOT * HDIM;
    short* Ocat = Vtb  + (size_t)HEADS * MTOT * HDIM; // 8192*896 (aliased with Wt)
    short* Wt   = Ocat;                               // 21*128*896, used only before attn
    short* Wob  = Ocat + (size_t)MTOT * HIDDEN;       // 896*896
    // compacted line-column K/V: 2 x 28*896*128 shorts = 12.85 MB, aliases dead xb
    short* Kc   = xb;
    short* Vc   = Kc + (size_t)28 * SCP * HDIM;

    prep_fused<<<NB_CASTX + NB_CASTWO + NB_TRANS, 256, 0, stream>>>(
        x, Wo, Wq, Wk, Wv, xb, Wob, Wt);
    qkv_gemm<<<dim3(21, MTOT / 128), 256, 0, stream>>>(xb, Wt, Qb, Kb, Vtb);
    compact_k<<<dim3(28, SCP / 32), 256, 0, stream>>>(Kb, Kc);
    compact_v<<<dim3(28, HDIM), 256, 0, stream>>>(Vtb, Vc);
    fano_attn<<<dim3(TT / 128, BB, HEADS), 256, 0, stream>>>(Qb, Kb, Vtb, Kc, Vc, Ocat, iscp);
    out_gemm<<<dim3(HIDDEN / 128, MTOT / 128), 256, 0, stream>>>(Ocat, Wob, out);
}

// Round 6
// 282.089 us; speedup vs baseline: 1.3620x; 1.1390x over previous
//
#include <hip/hip_runtime.h>
#include <hip/hip_bf16.h>

#define HIDDEN 896
#define HEADS 7
#define HDIM 128
#define BB 4
#define TT 2048
#define MTOT (BB*TT)   // 8192

// attn LDS strides (shorts). 132/68/68 measured best (975K conflicts).
#define KSP 132
#define VSP 68
#define PSP 68

#define SCP 896        // compacted line-column buffer: padded length (>= 879, mult of 64)

typedef short bf16x8 __attribute__((ext_vector_type(8)));
typedef float f32x4 __attribute__((ext_vector_type(4)));

__device__ __forceinline__ short f2bf(float f) {
    union { float f; unsigned u; } v; v.f = f;
    unsigned r = (v.u + 0x7FFF + ((v.u >> 16) & 1)) >> 16;
    return (short)r;
}

// async global->LDS, 16B per lane; lds dst must be wave-uniform base (+lane*16 implicit)
__device__ __forceinline__ void gll16(const short* g, short* l) {
    __builtin_amdgcn_global_load_lds(
        (const __attribute__((address_space(1))) unsigned int*)g,
        (__attribute__((address_space(3))) unsigned int*)l, 16, 0, 0);
}

// line membership: head h attends column s iff bit (s%7) of m_h set, m_h = {h,h+1,h+3} mod 7
__device__ __forceinline__ unsigned linemask(int h) {
    return ((0x0Bu << h) | (0x0Bu >> (7 - h))) & 0x7Fu;
}
// number of line columns with s < X  (X >= 0)
__device__ __forceinline__ int linecnt(unsigned m, int X) {
    return (X / 7) * 3 + __popc(m & ((1u << (X % 7)) - 1u));
}

// ---------------- kernel 1: fused prep (cast x, cast Wo, transpose-cast Wq/Wk/Wv) ----
#define NB_CASTX (MTOT * HIDDEN / 1024)      // 7168
#define NB_CASTWO (HIDDEN * HIDDEN / 1024)   // 784
#define NB_TRANS (28 * 4 * 21)               // 2352
__global__ __launch_bounds__(256) void prep_fused(
    const float* __restrict__ x, const float* __restrict__ Wo,
    const float* __restrict__ Wq, const float* __restrict__ Wk,
    const float* __restrict__ Wv,
    short* __restrict__ xb, short* __restrict__ Wob, short* __restrict__ Wt)
{
    __shared__ float tile[32][33];
    const int bid = blockIdx.x;
    if (bid < NB_CASTX) {
        int base = (bid * 256 + threadIdx.x) * 4;
        float4 v = *(const float4*)(x + base);
        short4 o;
        o.x = f2bf(v.x); o.y = f2bf(v.y); o.z = f2bf(v.z); o.w = f2bf(v.w);
        *(short4*)(xb + base) = o;
    } else if (bid < NB_CASTX + NB_CASTWO) {
        int base = ((bid - NB_CASTX) * 256 + threadIdx.x) * 4;
        float4 v = *(const float4*)(Wo + base);
        short4 o;
        o.x = f2bf(v.x); o.y = f2bf(v.y); o.z = f2bf(v.z); o.w = f2bf(v.w);
        *(short4*)(Wob + base) = o;
    } else {
        int t = bid - NB_CASTX - NB_CASTWO;
        const int z = t / 112;               // 0..20
        const int rem = t % 112;
        const int bx = rem % 28, by = rem / 28;
        const int type = z / 7, head = z % 7;
        const float* src = (type == 0 ? Wq : (type == 1 ? Wk : Wv)) + head * (HIDDEN * HDIM);
        short* dst = Wt + (size_t)z * (HDIM * HIDDEN);
        const int r0 = bx * 32, c0 = by * 32;
        const int tx = threadIdx.x & 31, ty = threadIdx.x >> 5;  // 32 x 8
        for (int i = 0; i < 4; i++)
            tile[ty * 4 + i][tx] = src[(r0 + ty * 4 + i) * HDIM + c0 + tx];
        __syncthreads();
        for (int i = 0; i < 4; i++)
            dst[(c0 + ty * 4 + i) * HIDDEN + r0 + tx] = f2bf(tile[tx][ty * 4 + i]);
    }
}

// ---------------- kernel 2: QKV projection GEMM ----------------
// XCD-bijective swizzle (1344 = 8*168): each XCD owns 8 m-tiles x all 21 z, so each
// A m-tile is fetched by exactly ONE XCD L2 (was 8x -> 160 MB FETCH). Pipelined
// K-loop: 3 LDS buffers, 1-deep global_load_lds prefetch, one raw s_barrier +
// counted vmcnt(4) per K-step (no full drain in the main loop).
__global__ __launch_bounds__(256) void qkv_gemm(
    const short* __restrict__ xb, const short* __restrict__ Wt,
    short* __restrict__ Q, short* __restrict__ Kk, short* __restrict__ Vt)
{
    __shared__ short Ash[3 * 128 * 32];
    __shared__ short Bsh[3 * 128 * 32];
    const int orig = blockIdx.x;
    const int sblk = (orig & 7) * 168 + (orig >> 3);   // bijective: 1344 % 8 == 0
    const int z = sblk % 21;
    const int m0 = (sblk / 21) * 128;
    const int head = z % 7, type = z / 7;
    const short* Wz = Wt + (size_t)z * (HDIM * HIDDEN);

    const int tid = threadIdx.x;
    const int wave = tid >> 6, lane = tid & 63;
    const int quad = lane >> 4, l16 = lane & 15;
    const int wm = (wave >> 1) * 64, wn = (wave & 1) * 64;

    f32x4 acc[4][4] = {};

    const int r0 = tid >> 2, cc0 = (tid & 3) * 8;
    const int r1 = r0 + 64;
    const short* asrc0 = xb + (size_t)(m0 + r0) * HIDDEN + cc0;
    const short* asrc1 = xb + (size_t)(m0 + r1) * HIDDEN + cc0;
    const short* bsrc0 = Wz + (size_t)r0 * HIDDEN + cc0;
    const short* bsrc1 = Wz + (size_t)r1 * HIDDEN + cc0;

    auto STAGE = [&](int kt, int sel) {
        const int ko = kt * 32;
        short* ab = Ash + sel * 4096;
        short* bb = Bsh + sel * 4096;
        gll16(asrc0 + ko, ab + wave * 512);
        gll16(asrc1 + ko, ab + 2048 + wave * 512);
        gll16(bsrc0 + ko, bb + wave * 512);
        gll16(bsrc1 + ko, bb + 2048 + wave * 512);
    };

    STAGE(0, 0);                        // prologue: tile 0 in flight
    const int NT = HIDDEN / 32;         // 28
    for (int t = 0; t < NT; t++) {
        const int sel = t % 3;
        if (t + 1 < NT) {
            STAGE(t + 1, (t + 1) % 3);  // overwrites tile t-2's buf (certified by barrier t-1)
            asm volatile("s_waitcnt vmcnt(4)" ::: "memory");   // my tile-t DMAs done
        } else {
            asm volatile("s_waitcnt vmcnt(0)" ::: "memory");
        }
        __builtin_amdgcn_s_barrier();   // everyone's tile-t DMAs done
        __builtin_amdgcn_sched_barrier(0);
        const short* ab = Ash + sel * 4096;
        const short* bb = Bsh + sel * 4096;
        bf16x8 af[4], bfr[4];
        for (int mi = 0; mi < 4; mi++)
            af[mi] = *(const bf16x8*)(ab + (wm + mi * 16 + l16) * 32 + quad * 8);
        for (int ni = 0; ni < 4; ni++)
            bfr[ni] = *(const bf16x8*)(bb + (wn + ni * 16 + l16) * 32 + quad * 8);
        for (int mi = 0; mi < 4; mi++)
            for (int ni = 0; ni < 4; ni++)
                acc[mi][ni] = __builtin_amdgcn_mfma_f32_16x16x32_bf16(af[mi], bfr[ni], acc[mi][ni], 0, 0, 0);
    }

    const size_t base = (size_t)head * (MTOT * HDIM);
    if (type == 0) {
        const float qs = 0.08838834764831845f * 1.4426950408889634f;
        for (int mi = 0; mi < 4; mi++)
            for (int ni = 0; ni < 4; ni++)
                for (int r = 0; r < 4; r++) {
                    int m = m0 + wm + mi * 16 + quad * 4 + r;
                    int n = wn + ni * 16 + l16;
                    Q[base + (size_t)m * HDIM + n] = f2bf(acc[mi][ni][r] * qs);
                }
    } else if (type == 1) {
        for (int mi = 0; mi < 4; mi++)
            for (int ni = 0; ni < 4; ni++)
                for (int r = 0; r < 4; r++) {
                    int m = m0 + wm + mi * 16 + quad * 4 + r;
                    int n = wn + ni * 16 + l16;
                    Kk[base + (size_t)m * HDIM + n] = f2bf(acc[mi][ni][r]);
                }
    } else {
        for (int mi = 0; mi < 4; mi++)
            for (int ni = 0; ni < 4; ni++) {
                int m = m0 + wm + mi * 16 + quad * 4;
                int bb2 = m >> 11, t = m & 2047;
                int n = wn + ni * 16 + l16;
                short4 o;
                o.x = f2bf(acc[mi][ni][0]); o.y = f2bf(acc[mi][ni][1]);
                o.z = f2bf(acc[mi][ni][2]); o.w = f2bf(acc[mi][ni][3]);
                *(short4*)(Vt + base + (size_t)bb2 * (HDIM * TT) + (size_t)n * TT + t) = o;
            }
    }
}

// ---------------- kernel 2.5a: compact K to line-columns (ascending s) ----------------
__global__ __launch_bounds__(256) void compact_k(const short* __restrict__ K,
                                                 short* __restrict__ Kc)
{
    const int hb = blockIdx.x, h = hb >> 2, b = hb & 3;
    const unsigned m = linemask(h);
    const int c_tot = 876 + __popc(m & 0xFu);
    const int o0 = __ffs(m) - 1;
    const unsigned m1 = m & (m - 1);
    const int o1 = __ffs(m1) - 1;
    const unsigned m2 = m1 & (m1 - 1);
    const int o2 = __ffs(m2) - 1;
    const int r = blockIdx.y * 32 + (threadIdx.x >> 3);
    const int c = (threadIdx.x & 7) * 16;
    short* dst = Kc + ((size_t)hb * SCP + r) * HDIM + c;
    if (r < c_tot) {
        int g = r / 3, id = r - g * 3;
        int s = g * 7 + (id == 0 ? o0 : (id == 1 ? o1 : o2));
        const short* src = K + (size_t)(h * MTOT + b * TT + s) * HDIM + c;
        *(bf16x8*)dst = *(const bf16x8*)src;
        *(bf16x8*)(dst + 8) = *(const bf16x8*)(src + 8);
    } else {
        bf16x8 zz = {};
        *(bf16x8*)dst = zz;
        *(bf16x8*)(dst + 8) = zz;
    }
}

// ---------------- kernel 2.5b: compact V^T to line-columns ----------------
__global__ __launch_bounds__(256) void compact_v(const short* __restrict__ Vt,
                                                 short* __restrict__ Vc)
{
    const int hb = blockIdx.x, h = hb >> 2, b = hb & 3;
    const int d = blockIdx.y;
    const unsigned m = linemask(h);
    const int c_tot = 876 + __popc(m & 0xFu);
    const int o0 = __ffs(m) - 1;
    const unsigned m1 = m & (m - 1);
    const int o1 = __ffs(m1) - 1;
    const unsigned m2 = m1 & (m1 - 1);
    const int o2 = __ffs(m2) - 1;
    const short* src = Vt + (size_t)h * MTOT * HDIM + (size_t)b * HDIM * TT + (size_t)d * TT;
    short* dst = Vc + ((size_t)hb * HDIM + d) * SCP;
    for (int sp = threadIdx.x * 4; sp < SCP; sp += 1024) {
        short4 o;
        short* po = (short*)&o;
        for (int j = 0; j < 4; j++) {
            int spp = sp + j;
            short v = 0;
            if (spp < c_tot) {
                int g = spp / 3, id = spp - g * 3;
                int s = g * 7 + (id == 0 ? o0 : (id == 1 ? o1 : o2));
                v = src[s];
            }
            po[j] = v;
        }
        *(short4*)(dst + sp) = o;
    }
}

// ---------------- kernel 3: fano flash attention v13 (line-compacted far phase) -------
__global__ __launch_bounds__(256) void fano_attn(
    const short* __restrict__ Q, const short* __restrict__ K, const short* __restrict__ Vt,
    const short* __restrict__ Kc, const short* __restrict__ Vc,
    short* __restrict__ Ocat, const int* __restrict__ iscp)
{
    __shared__ short Ks[64 * KSP];
    __shared__ short Vs[128 * VSP];
    __shared__ short Ps[4][32 * PSP];

    const int causal = *iscp;
    const int mlin = blockIdx.y + 4 * blockIdx.z;   // b + 4h in [0,28)
    const int qt = (causal && mlin >= 16) ? ((int)gridDim.x - 1 - blockIdx.x)
                                          : (int)blockIdx.x;
    const int q0 = qt * 128;
    const int b = blockIdx.y, h = blockIdx.z;
    const int hb = h * 4 + b;
    const int tid = threadIdx.x, wave = tid >> 6, lane = tid & 63;
    const int quad = lane >> 4, l16 = lane & 15;
    const int iw = q0 + wave * 32;

    const short* Qb = Q + (size_t)(h * MTOT + b * TT + q0) * HDIM;
    const short* Kb = K + (size_t)(h * MTOT + b * TT) * HDIM;
    const short* Vb = Vt + (size_t)h * MTOT * HDIM + (size_t)b * HDIM * TT;
    const short* Kcb = Kc + (size_t)hb * SCP * HDIM;
    const short* Vcb = Vc + (size_t)hb * HDIM * SCP;

    bf16x8 qf[2][4];
    for (int g = 0; g < 2; g++)
        for (int ks = 0; ks < 4; ks++)
            qf[g][ks] = *(const bf16x8*)(Qb + (size_t)(wave * 32 + g * 16 + l16) * HDIM + ks * 32 + quad * 8);

    f32x4 oacc[2][8] = {};
    f32x4 lacc[2] = {};
    int irow[2][4];
    for (int g = 0; g < 2; g++)
        for (int r = 0; r < 4; r++)
            irow[g][r] = q0 + wave * 32 + g * 16 + quad * 4 + r;

    const bf16x8 vones = {0x3F80, 0x3F80, 0x3F80, 0x3F80, 0x3F80, 0x3F80, 0x3F80, 0x3F80};

    int krow[4], kcol[4], vrow[4], vcol[4];
    for (int i = 0; i < 4; i++) {
        int c = tid + i * 256;
        krow[i] = c >> 4; kcol[i] = (c & 15) * 8;
        vrow[i] = c >> 3; vcol[i] = (c & 7) * 8;
    }

    const unsigned m_h = linemask(h);
    const int c_tot = 876 + __popc(m_h & 0xFu);
    const int sB0 = (causal && q0 >= 64) ? (q0 - 64) : 0;
    const int sB1 = causal ? (q0 + 128) : (q0 + 192 < TT ? q0 + 192 : TT);
    const int cA = linecnt(m_h, sB0);
    const int cC0 = causal ? c_tot : linecnt(m_h, sB1);
    const int l16h = (l16 - h + 7) % 7;

    short* Pw = &Ps[wave][0];

    const int nph = causal ? 2 : 3;
    for (int p = 0; p < nph; p++) {
        const short *Kp, *Vp;
        int vstr, t0, t1, c0v = 0, c1v = 0;
        if (p == 0)      { Kp = Kcb; Vp = Vcb; vstr = SCP; t0 = 0;        t1 = (cA + 63) >> 6;    c0v = 0;   c1v = cA; }
        else if (p == 1) { Kp = Kb;  Vp = Vb;  vstr = TT;  t0 = sB0 >> 6; t1 = sB1 >> 6; }
        else             { Kp = Kcb; Vp = Vcb; vstr = SCP; t0 = cC0 >> 6; t1 = (c_tot + 63) >> 6; c0v = cC0; c1v = c_tot; }
        if (t0 >= t1) continue;
        const bool comp = (p != 1);
        int s0q = sB0 % 7;

        bf16x8 kreg[4], vreg[4];
        {
            const int si = t0 * 64;
            for (int i = 0; i < 4; i++) {
                kreg[i] = *(const bf16x8*)(Kp + (size_t)(si + krow[i]) * HDIM + kcol[i]);
                vreg[i] = *(const bf16x8*)(Vp + (size_t)vrow[i] * vstr + si + vcol[i]);
            }
        }

        for (int t = t0; t < t1; t++) {
            const int s0 = t * 64;
            __syncthreads();
            for (int i = 0; i < 4; i++) {
                *(bf16x8*)(Ks + krow[i] * KSP + kcol[i]) = kreg[i];
                *(bf16x8*)(Vs + vrow[i] * VSP + vcol[i]) = vreg[i];
            }
            __syncthreads();

            int tn = t + 1; if (tn >= t1) tn = t0;
            const int sn = tn * 64;
            for (int i = 0; i < 4; i++) {
                kreg[i] = *(const bf16x8*)(Kp + (size_t)(sn + krow[i]) * HDIM + kcol[i]);
                vreg[i] = *(const bf16x8*)(Vp + (size_t)vrow[i] * vstr + sn + vcol[i]);
            }

            f32x4 sacc[2][4] = {};
            for (int ni = 0; ni < 4; ni++)
                for (int ks = 0; ks < 4; ks++) {
                    bf16x8 bk = *(const bf16x8*)(Ks + (ni * 16 + l16) * KSP + ks * 32 + quad * 8);
                    sacc[0][ni] = __builtin_amdgcn_mfma_f32_16x16x32_bf16(qf[0][ks], bk, sacc[0][ni], 0, 0, 0);
                    sacc[1][ni] = __builtin_amdgcn_mfma_f32_16x16x32_bf16(qf[1][ks], bk, sacc[1][ni], 0, 0, 0);
                }

            if (comp) {
                for (int ni = 0; ni < 4; ni++) {
                    int scol = s0 + ni * 16 + l16;
                    bool ok = (scol >= c0v) & (scol < c1v);
                    for (int g = 0; g < 2; g++)
                        for (int r = 0; r < 4; r++)
                            sacc[g][ni][r] = ok ? exp2f(sacc[g][ni][r]) : 0.0f;
                }
            } else {
                int d7b = l16h + s0q; if (d7b >= 7) d7b -= 7;
                for (int ni = 0; ni < 4; ni++) {
                    int d7 = d7b + 2 * ni; if (d7 >= 7) d7 -= 7;
                    bool line = (0x0B >> d7) & 1;
                    int s = s0 + ni * 16 + l16;
                    for (int g = 0; g < 2; g++)
                        for (int r = 0; r < 4; r++) {
                            int i = irow[g][r];
                            bool ok = causal ? ((s <= i) & (line | (s >= i - 16)))
                                             : (line | ((s >= i - 16) & (s <= i + 16)));
                            sacc[g][ni][r] = ok ? exp2f(sacc[g][ni][r]) : 0.0f;
                        }
                }
                s0q++; if (s0q == 7) s0q = 0;
            }

            for (int g = 0; g < 2; g++)
                for (int ni = 0; ni < 4; ni++)
                    for (int r = 0; r < 4; r++)
                        Pw[(g * 16 + quad * 4 + r) * PSP + ni * 16 + l16] = f2bf(sacc[g][ni][r]);

            for (int ks2 = 0; ks2 < 2; ks2++) {
                bf16x8 ap0 = *(const bf16x8*)(Pw + l16 * PSP + ks2 * 32 + quad * 8);
                bf16x8 ap1 = *(const bf16x8*)(Pw + (16 + l16) * PSP + ks2 * 32 + quad * 8);
                lacc[0] = __builtin_amdgcn_mfma_f32_16x16x32_bf16(ap0, vones, lacc[0], 0, 0, 0);
                lacc[1] = __builtin_amdgcn_mfma_f32_16x16x32_bf16(ap1, vones, lacc[1], 0, 0, 0);
                for (int nj = 0; nj < 8; nj++) {
                    bf16x8 bv = *(const bf16x8*)(Vs + (nj * 16 + l16) * VSP + ks2 * 32 + quad * 8);
                    oacc[0][nj] = __builtin_amdgcn_mfma_f32_16x16x32_bf16(ap0, bv, oacc[0][nj], 0, 0, 0);
                    oacc[1][nj] = __builtin_amdgcn_mfma_f32_16x16x32_bf16(ap1, bv, oacc[1][nj], 0, 0, 0);
                }
            }
        }
    }

    short* Obase = Ocat + (size_t)(b * TT) * HIDDEN + h * HDIM;
    for (int g = 0; g < 2; g++) {
        float inv[4];
        for (int r = 0; r < 4; r++) inv[r] = 1.0f / lacc[g][r];
        for (int nj = 0; nj < 8; nj++)
            for (int r = 0; r < 4; r++)
                Obase[(size_t)irow[g][r] * HIDDEN + nj * 16 + l16] = f2bf(oacc[g][nj][r] * inv[r]);
    }
}

// ---------------- kernel 4: output projection ----------------
// XCD swizzle (448 = 8*56): 8 m-tiles per XCD, 7 B panels (1.6 MB) L2-resident.
// Same pipelined 3-buffer single-barrier K-loop as qkv_gemm.
__global__ __launch_bounds__(256) void out_gemm(
    const short* __restrict__ A, const short* __restrict__ Bt, float* __restrict__ out)
{
    __shared__ short Ash[3 * 128 * 32];
    __shared__ short Bsh[3 * 128 * 32];
    const int orig = blockIdx.x;
    const int sblk = (orig & 7) * 56 + (orig >> 3);   // bijective: 448 % 8 == 0
    const int n0 = (sblk % 7) * 128;
    const int m0 = (sblk / 7) * 128;

    const int tid = threadIdx.x;
    const int wave = tid >> 6, lane = tid & 63;
    const int quad = lane >> 4, l16 = lane & 15;
    const int wm = (wave >> 1) * 64, wn = (wave & 1) * 64;

    f32x4 acc[4][4] = {};

    const int r0 = tid >> 2, cc0 = (tid & 3) * 8;
    const int r1 = r0 + 64;
    const short* asrc0 = A + (size_t)(m0 + r0) * HIDDEN + cc0;
    const short* asrc1 = A + (size_t)(m0 + r1) * HIDDEN + cc0;
    const short* bsrc0 = Bt + (size_t)(n0 + r0) * HIDDEN + cc0;
    const short* bsrc1 = Bt + (size_t)(n0 + r1) * HIDDEN + cc0;

    auto STAGE = [&](int kt, int sel) {
        const int ko = kt * 32;
        short* ab = Ash + sel * 4096;
        short* bb = Bsh + sel * 4096;
        gll16(asrc0 + ko, ab + wave * 512);
        gll16(asrc1 + ko, ab + 2048 + wave * 512);
        gll16(bsrc0 + ko, bb + wave * 512);
        gll16(bsrc1 + ko, bb + 2048 + wave * 512);
    };

    STAGE(0, 0);
    const int NT = HIDDEN / 32;         // 28
    for (int t = 0; t < NT; t++) {
        const int sel = t % 3;
        if (t + 1 < NT) {
            STAGE(t + 1, (t + 1) % 3);
            asm volatile("s_waitcnt vmcnt(4)" ::: "memory");
        } else {
            asm volatile("s_waitcnt vmcnt(0)" ::: "memory");
        }
        __builtin_amdgcn_s_barrier();
        __builtin_amdgcn_sched_barrier(0);
        const short* ab = Ash + sel * 4096;
        const short* bb = Bsh + sel * 4096;
        bf16x8 af[4], bfr[4];
        for (int mi = 0; mi < 4; mi++)
            af[mi] = *(const bf16x8*)(ab + (wm + mi * 16 + l16) * 32 + quad * 8);
        for (int ni = 0; ni < 4; ni++)
            bfr[ni] = *(const bf16x8*)(bb + (wn + ni * 16 + l16) * 32 + quad * 8);
        for (int mi = 0; mi < 4; mi++)
            for (int ni = 0; ni < 4; ni++)
                acc[mi][ni] = __builtin_amdgcn_mfma_f32_16x16x32_bf16(af[mi], bfr[ni], acc[mi][ni], 0, 0, 0);
    }

    for (int mi = 0; mi < 4; mi++)
        for (int ni = 0; ni < 4; ni++)
            for (int r = 0; r < 4; r++) {
                int m = m0 + wm + mi * 16 + quad * 4 + r;
                int n = n0 + wn + ni * 16 + l16;
                out[(size_t)m * HIDDEN + n] = acc[mi][ni][r];
            }
}

extern "C" void kernel_launch(void* const* d_in, const int* in_sizes, int n_in,
                              void* d_out, int out_size, void* d_ws, size_t ws_size,
                              hipStream_t stream) {
    (void)in_sizes; (void)n_in; (void)out_size; (void)ws_size;
    const float* x  = (const float*)d_in[0];
    const float* Wq = (const float*)d_in[1];
    const float* Wk = (const float*)d_in[2];
    const float* Wv = (const float*)d_in[3];
    const float* Wo = (const float*)d_in[4];
    const int* iscp = (const int*)d_in[5];
    float* out = (float*)d_out;

    short* xb   = (short*)d_ws;                       // 8192*896 shorts = 14.68 MB
    short* Qb   = xb   + (size_t)MTOT * HIDDEN;       // 7*8192*128 each
    short* Kb   = Qb   + (size_t)HEADS * MTOT * HDIM;
    short* Vtb  = Kb   + (size_t)HEADS * MTOT * HDIM;
    short* Ocat = Vtb  + (size_t)HEADS * MTOT * HDIM; // 8192*896 (aliased with Wt)
    short* Wt   = Ocat;                               // 21*128*896, used only before attn
    short* Wob  = Ocat + (size_t)MTOT * HIDDEN;       // 896*896
    // compacted line-column K/V: 2 x 28*896*128 shorts = 12.85 MB, aliases dead xb
    short* Kc   = xb;
    short* Vc   = Kc + (size_t)28 * SCP * HDIM;

    prep_fused<<<NB_CASTX + NB_CASTWO + NB_TRANS, 256, 0, stream>>>(
        x, Wo, Wq, Wk, Wv, xb, Wob, Wt);
    qkv_gemm<<<21 * (MTOT / 128), 256, 0, stream>>>(xb, Wt, Qb, Kb, Vtb);
    compact_k<<<dim3(28, SCP / 32), 256, 0, stream>>>(Kb, Kc);
    compact_v<<<dim3(28, HDIM), 256, 0, stream>>>(Vtb, Vc);
    fano_attn<<<dim3(TT / 128, BB, HEADS), 256, 0, stream>>>(Qb, Kb, Vtb, Kc, Vc, Ocat, iscp);
    out_gemm<<<(HIDDEN / 128) * (MTOT / 128), 256, 0, stream>>>(Ocat, Wob, out);
}

// Round 7
// 279.636 us; speedup vs baseline: 1.3739x; 1.0088x over previous
//
#include <hip/hip_runtime.h>
#include <hip/hip_bf16.h>

#define HIDDEN 896
#define HEADS 7
#define HDIM 128
#define BB 4
#define TT 2048
#define MTOT (BB*TT)   // 8192

#define SCP 896        // compacted line-column buffer: padded length (>= 879, mult of 64)

typedef short bf16x8 __attribute__((ext_vector_type(8)));
typedef float f32x4 __attribute__((ext_vector_type(4)));

__device__ __forceinline__ short f2bf(float f) {
    union { float f; unsigned u; } v; v.f = f;
    unsigned r = (v.u + 0x7FFF + ((v.u >> 16) & 1)) >> 16;
    return (short)r;
}

// async global->LDS, 16B per lane; lds dst must be wave-uniform base (+lane*16 implicit)
__device__ __forceinline__ void gll16(const short* g, short* l) {
    __builtin_amdgcn_global_load_lds(
        (const __attribute__((address_space(1))) unsigned int*)g,
        (__attribute__((address_space(3))) unsigned int*)l, 16, 0, 0);
}

// line membership: head h attends column s iff bit (s%7) of m_h set, m_h = {h,h+1,h+3} mod 7
__device__ __forceinline__ unsigned linemask(int h) {
    return ((0x0Bu << h) | (0x0Bu >> (7 - h))) & 0x7Fu;
}
// number of line columns with s < X  (X >= 0)
__device__ __forceinline__ int linecnt(unsigned m, int X) {
    return (X / 7) * 3 + __popc(m & ((1u << (X % 7)) - 1u));
}

// ---------------- kernel 1: fused prep (cast x, cast Wo, transpose-cast Wq/Wk/Wv) ----
#define NB_CASTX (MTOT * HIDDEN / 1024)      // 7168
#define NB_CASTWO (HIDDEN * HIDDEN / 1024)   // 784
#define NB_TRANS (28 * 4 * 21)               // 2352
__global__ __launch_bounds__(256) void prep_fused(
    const float* __restrict__ x, const float* __restrict__ Wo,
    const float* __restrict__ Wq, const float* __restrict__ Wk,
    const float* __restrict__ Wv,
    short* __restrict__ xb, short* __restrict__ Wob, short* __restrict__ Wt)
{
    __shared__ float tile[32][33];
    const int bid = blockIdx.x;
    if (bid < NB_CASTX) {
        int base = (bid * 256 + threadIdx.x) * 4;
        float4 v = *(const float4*)(x + base);
        short4 o;
        o.x = f2bf(v.x); o.y = f2bf(v.y); o.z = f2bf(v.z); o.w = f2bf(v.w);
        *(short4*)(xb + base) = o;
    } else if (bid < NB_CASTX + NB_CASTWO) {
        int base = ((bid - NB_CASTX) * 256 + threadIdx.x) * 4;
        float4 v = *(const float4*)(Wo + base);
        short4 o;
        o.x = f2bf(v.x); o.y = f2bf(v.y); o.z = f2bf(v.z); o.w = f2bf(v.w);
        *(short4*)(Wob + base) = o;
    } else {
        int t = bid - NB_CASTX - NB_CASTWO;
        const int z = t / 112;               // 0..20
        const int rem = t % 112;
        const int bx = rem % 28, by = rem / 28;
        const int type = z / 7, head = z % 7;
        const float* src = (type == 0 ? Wq : (type == 1 ? Wk : Wv)) + head * (HIDDEN * HDIM);
        short* dst = Wt + (size_t)z * (HDIM * HIDDEN);
        const int r0 = bx * 32, c0 = by * 32;
        const int tx = threadIdx.x & 31, ty = threadIdx.x >> 5;  // 32 x 8
        for (int i = 0; i < 4; i++)
            tile[ty * 4 + i][tx] = src[(r0 + ty * 4 + i) * HDIM + c0 + tx];
        __syncthreads();
        for (int i = 0; i < 4; i++)
            dst[(c0 + ty * 4 + i) * HIDDEN + r0 + tx] = f2bf(tile[tx][ty * 4 + i]);
    }
}

// ---------------- kernel 2: QKV projection GEMM (r6 proven: XCD swizzle + pipeline) --
__global__ __launch_bounds__(256) void qkv_gemm(
    const short* __restrict__ xb, const short* __restrict__ Wt,
    short* __restrict__ Q, short* __restrict__ Kk, short* __restrict__ Vt)
{
    __shared__ short Ash[3 * 128 * 32];
    __shared__ short Bsh[3 * 128 * 32];
    const int orig = blockIdx.x;
    const int sblk = (orig & 7) * 168 + (orig >> 3);   // bijective: 1344 % 8 == 0
    const int z = sblk % 21;
    const int m0 = (sblk / 21) * 128;
    const int head = z % 7, type = z / 7;
    const short* Wz = Wt + (size_t)z * (HDIM * HIDDEN);

    const int tid = threadIdx.x;
    const int wave = tid >> 6, lane = tid & 63;
    const int quad = lane >> 4, l16 = lane & 15;
    const int wm = (wave >> 1) * 64, wn = (wave & 1) * 64;

    f32x4 acc[4][4] = {};

    const int r0 = tid >> 2, cc0 = (tid & 3) * 8;
    const int r1 = r0 + 64;
    const short* asrc0 = xb + (size_t)(m0 + r0) * HIDDEN + cc0;
    const short* asrc1 = xb + (size_t)(m0 + r1) * HIDDEN + cc0;
    const short* bsrc0 = Wz + (size_t)r0 * HIDDEN + cc0;
    const short* bsrc1 = Wz + (size_t)r1 * HIDDEN + cc0;

    auto STAGE = [&](int kt, int sel) {
        const int ko = kt * 32;
        short* ab = Ash + sel * 4096;
        short* bb = Bsh + sel * 4096;
        gll16(asrc0 + ko, ab + wave * 512);
        gll16(asrc1 + ko, ab + 2048 + wave * 512);
        gll16(bsrc0 + ko, bb + wave * 512);
        gll16(bsrc1 + ko, bb + 2048 + wave * 512);
    };

    STAGE(0, 0);
    const int NT = HIDDEN / 32;         // 28
    for (int t = 0; t < NT; t++) {
        const int sel = t % 3;
        if (t + 1 < NT) {
            STAGE(t + 1, (t + 1) % 3);
            asm volatile("s_waitcnt vmcnt(4)" ::: "memory");
        } else {
            asm volatile("s_waitcnt vmcnt(0)" ::: "memory");
        }
        __builtin_amdgcn_s_barrier();
        __builtin_amdgcn_sched_barrier(0);
        const short* ab = Ash + sel * 4096;
        const short* bb = Bsh + sel * 4096;
        bf16x8 af[4], bfr[4];
        for (int mi = 0; mi < 4; mi++)
            af[mi] = *(const bf16x8*)(ab + (wm + mi * 16 + l16) * 32 + quad * 8);
        for (int ni = 0; ni < 4; ni++)
            bfr[ni] = *(const bf16x8*)(bb + (wn + ni * 16 + l16) * 32 + quad * 8);
        for (int mi = 0; mi < 4; mi++)
            for (int ni = 0; ni < 4; ni++)
                acc[mi][ni] = __builtin_amdgcn_mfma_f32_16x16x32_bf16(af[mi], bfr[ni], acc[mi][ni], 0, 0, 0);
    }

    const size_t base = (size_t)head * (MTOT * HDIM);
    if (type == 0) {
        const float qs = 0.08838834764831845f * 1.4426950408889634f;
        for (int mi = 0; mi < 4; mi++)
            for (int ni = 0; ni < 4; ni++)
                for (int r = 0; r < 4; r++) {
                    int m = m0 + wm + mi * 16 + quad * 4 + r;
                    int n = wn + ni * 16 + l16;
                    Q[base + (size_t)m * HDIM + n] = f2bf(acc[mi][ni][r] * qs);
                }
    } else if (type == 1) {
        for (int mi = 0; mi < 4; mi++)
            for (int ni = 0; ni < 4; ni++)
                for (int r = 0; r < 4; r++) {
                    int m = m0 + wm + mi * 16 + quad * 4 + r;
                    int n = wn + ni * 16 + l16;
                    Kk[base + (size_t)m * HDIM + n] = f2bf(acc[mi][ni][r]);
                }
    } else {
        for (int mi = 0; mi < 4; mi++)
            for (int ni = 0; ni < 4; ni++) {
                int m = m0 + wm + mi * 16 + quad * 4;
                int bb2 = m >> 11, t = m & 2047;
                int n = wn + ni * 16 + l16;
                short4 o;
                o.x = f2bf(acc[mi][ni][0]); o.y = f2bf(acc[mi][ni][1]);
                o.z = f2bf(acc[mi][ni][2]); o.w = f2bf(acc[mi][ni][3]);
                *(short4*)(Vt + base + (size_t)bb2 * (HDIM * TT) + (size_t)n * TT + t) = o;
            }
    }
}

// ---------------- kernel 2.5a: compact K to line-columns (ascending s) ----------------
__global__ __launch_bounds__(256) void compact_k(const short* __restrict__ K,
                                                 short* __restrict__ Kc)
{
    const int hb = blockIdx.x, h = hb >> 2, b = hb & 3;
    const unsigned m = linemask(h);
    const int c_tot = 876 + __popc(m & 0xFu);
    const int o0 = __ffs(m) - 1;
    const unsigned m1 = m & (m - 1);
    const int o1 = __ffs(m1) - 1;
    const unsigned m2 = m1 & (m1 - 1);
    const int o2 = __ffs(m2) - 1;
    const int r = blockIdx.y * 32 + (threadIdx.x >> 3);
    const int c = (threadIdx.x & 7) * 16;
    short* dst = Kc + ((size_t)hb * SCP + r) * HDIM + c;
    if (r < c_tot) {
        int g = r / 3, id = r - g * 3;
        int s = g * 7 + (id == 0 ? o0 : (id == 1 ? o1 : o2));
        const short* src = K + (size_t)(h * MTOT + b * TT + s) * HDIM + c;
        *(bf16x8*)dst = *(const bf16x8*)src;
        *(bf16x8*)(dst + 8) = *(const bf16x8*)(src + 8);
    } else {
        bf16x8 zz = {};
        *(bf16x8*)dst = zz;
        *(bf16x8*)(dst + 8) = zz;
    }
}

// ---------------- kernel 2.5b: compact V^T to line-columns ----------------
__global__ __launch_bounds__(256) void compact_v(const short* __restrict__ Vt,
                                                 short* __restrict__ Vc)
{
    const int hb = blockIdx.x, h = hb >> 2, b = hb & 3;
    const int d = blockIdx.y;
    const unsigned m = linemask(h);
    const int c_tot = 876 + __popc(m & 0xFu);
    const int o0 = __ffs(m) - 1;
    const unsigned m1 = m & (m - 1);
    const int o1 = __ffs(m1) - 1;
    const unsigned m2 = m1 & (m1 - 1);
    const int o2 = __ffs(m2) - 1;
    const short* src = Vt + (size_t)h * MTOT * HDIM + (size_t)b * HDIM * TT + (size_t)d * TT;
    short* dst = Vc + ((size_t)hb * HDIM + d) * SCP;
    for (int sp = threadIdx.x * 4; sp < SCP; sp += 1024) {
        short4 o;
        short* po = (short*)&o;
        for (int j = 0; j < 4; j++) {
            int spp = sp + j;
            short v = 0;
            if (spp < c_tot) {
                int g = spp / 3, id = spp - g * 3;
                int s = g * 7 + (id == 0 ? o0 : (id == 1 ? o1 : o2));
                v = src[s];
            }
            po[j] = v;
        }
        *(short4*)(dst + sp) = o;
    }
}

// ---------------- kernel 3: fano flash attention v14 (DMA-pipelined steps) ----------
// K/V staged via global_load_lds into LINEAR double-buffered tiles with inverse-swizzled
// global source + XOR-swizzled reads (chunk ^= row&7 on 16B chunks). One raw s_barrier
// + vmcnt(0) per step; stage(t+1) issued AFTER the barrier (double-buffer safe: barrier
// certifies all waves consumed tile t-1). Prefetch crosses phase boundaries.
// LDS: Ks 2x64x128 + Vs 2x128x64 + Ps 4x32x64 = 80 KiB exactly -> 2 blocks/CU.
__global__ __launch_bounds__(256) void fano_attn(
    const short* __restrict__ Q, const short* __restrict__ K, const short* __restrict__ Vt,
    const short* __restrict__ Kc, const short* __restrict__ Vc,
    short* __restrict__ Ocat, const int* __restrict__ iscp)
{
    __shared__ short Ks[2 * 64 * 128];
    __shared__ short Vs[2 * 128 * 64];
    __shared__ short Ps[4 * 2048];

    const int causal = *iscp;
    const int mlin = blockIdx.y + 4 * blockIdx.z;   // b + 4h in [0,28)
    const int qt = (causal && mlin >= 16) ? ((int)gridDim.x - 1 - blockIdx.x)
                                          : (int)blockIdx.x;
    const int q0 = qt * 128;
    const int b = blockIdx.y, h = blockIdx.z;
    const int hb = h * 4 + b;
    const int tid = threadIdx.x, wave = tid >> 6, lane = tid & 63;
    const int quad = lane >> 4, l16 = lane & 15;
    const int iw = q0 + wave * 32;
    const int swz = l16 & 7;            // row&7 for all read rows (row = X*16 + l16)

    const short* Qb = Q + (size_t)(h * MTOT + b * TT + q0) * HDIM;
    const short* Kb = K + (size_t)(h * MTOT + b * TT) * HDIM;
    const short* Vb = Vt + (size_t)h * MTOT * HDIM + (size_t)b * HDIM * TT;
    const short* Kcb = Kc + (size_t)hb * SCP * HDIM;
    const short* Vcb = Vc + (size_t)hb * HDIM * SCP;

    // stage-source precompute: linear LDS chunk c = (wave*4+i)*64 + lane
    // K tile [64 rows][16 chunks]; V tile [128 rows][8 chunks]; src chunk ^= row&7
    int krowS[4], kccS[4], vrowS[4], vccS[4];
    for (int i = 0; i < 4; i++) {
        int c = (wave * 4 + i) * 64 + lane;
        krowS[i] = c >> 4; kccS[i] = ((c & 15) ^ (krowS[i] & 7)) * 8;
        vrowS[i] = c >> 3; vccS[i] = ((c & 7) ^ (vrowS[i] & 7)) * 8;
    }

    auto STAGE = [&](const short* Kp, const short* Vp, int vstr, int s0, int sel) {
        short* kb = Ks + sel * 8192;
        short* vb = Vs + sel * 8192;
        for (int i = 0; i < 4; i++) {
            gll16(Kp + (size_t)(s0 + krowS[i]) * HDIM + kccS[i], kb + (wave * 4 + i) * 512);
            gll16(Vp + (size_t)vrowS[i] * vstr + s0 + vccS[i], vb + (wave * 4 + i) * 512);
        }
    };

    bf16x8 qf[2][4];
    for (int g = 0; g < 2; g++)
        for (int ks = 0; ks < 4; ks++)
            qf[g][ks] = *(const bf16x8*)(Qb + (size_t)(wave * 32 + g * 16 + l16) * HDIM + ks * 32 + quad * 8);

    f32x4 oacc[2][8] = {};
    f32x4 lacc[2] = {};
    int irow[2][4];
    for (int g = 0; g < 2; g++)
        for (int r = 0; r < 4; r++)
            irow[g][r] = q0 + wave * 32 + g * 16 + quad * 4 + r;

    const bf16x8 vones = {0x3F80, 0x3F80, 0x3F80, 0x3F80, 0x3F80, 0x3F80, 0x3F80, 0x3F80};

    const unsigned m_h = linemask(h);
    const int c_tot = 876 + __popc(m_h & 0xFu);
    const int sB0 = (causal && q0 >= 64) ? (q0 - 64) : 0;
    const int sB1 = causal ? (q0 + 128) : (q0 + 192 < TT ? q0 + 192 : TT);
    const int cA = linecnt(m_h, sB0);
    const int cC0 = causal ? c_tot : linecnt(m_h, sB1);
    const int l16h = (l16 - h + 7) % 7;

    // phase list (only nonempty phases); phase-level arrays accessed ~once per phase
    const short* Kpa[3]; const short* Vpa[3];
    int vstra[3], ta0[3], ta1[3], cv0a[3], cv1a[3], cmpa[3];
    int np = 0;
    {
        int t1A = (cA + 63) >> 6;
        if (t1A > 0) { Kpa[np] = Kcb; Vpa[np] = Vcb; vstra[np] = SCP; ta0[np] = 0; ta1[np] = t1A; cv0a[np] = 0; cv1a[np] = cA; cmpa[np] = 1; np++; }
    }
    {
        int t0B = sB0 >> 6, t1B = sB1 >> 6;
        if (t1B > t0B) { Kpa[np] = Kb; Vpa[np] = Vb; vstra[np] = TT; ta0[np] = t0B; ta1[np] = t1B; cv0a[np] = 0; cv1a[np] = 0; cmpa[np] = 0; np++; }
    }
    if (!causal) {
        int t0C = cC0 >> 6, t1C = (c_tot + 63) >> 6;
        if (t1C > t0C) { Kpa[np] = Kcb; Vpa[np] = Vcb; vstra[np] = SCP; ta0[np] = t0C; ta1[np] = t1C; cv0a[np] = cC0; cv1a[np] = c_tot; cmpa[np] = 1; np++; }
    }

    short* Pw = Ps + wave * 2048;
    int cur = 0;
    STAGE(Kpa[0], Vpa[0], vstra[0], ta0[0] * 64, 0);

    for (int pi = 0; pi < np; pi++) {
        const short* Kp_ = Kpa[pi];
        const short* Vp_ = Vpa[pi];
        const int vstr_ = vstra[pi], t1_ = ta1[pi];
        const int comp = cmpa[pi], c0v = cv0a[pi], c1v = cv1a[pi];
        for (int t = ta0[pi]; t < t1_; t++) {
            asm volatile("s_waitcnt vmcnt(0)" ::: "memory");   // my tile-t DMAs done (issued last step)
            __builtin_amdgcn_s_barrier();                      // all waves: t ready, t-1 consumed
            __builtin_amdgcn_sched_barrier(0);
            if (t + 1 < t1_)
                STAGE(Kp_, Vp_, vstr_, (t + 1) * 64, cur ^ 1);
            else if (pi + 1 < np)
                STAGE(Kpa[pi + 1], Vpa[pi + 1], vstra[pi + 1], ta0[pi + 1] * 64, cur ^ 1);

            const short* KsC = Ks + cur * 8192;
            const short* VsC = Vs + cur * 8192;
            const int s0 = t * 64;

            f32x4 sacc[2][4] = {};
            for (int ni = 0; ni < 4; ni++)
                for (int ks = 0; ks < 4; ks++) {
                    bf16x8 bk = *(const bf16x8*)(KsC + (ni * 16 + l16) * 128 + ((ks * 4 + quad) ^ swz) * 8);
                    sacc[0][ni] = __builtin_amdgcn_mfma_f32_16x16x32_bf16(qf[0][ks], bk, sacc[0][ni], 0, 0, 0);
                    sacc[1][ni] = __builtin_amdgcn_mfma_f32_16x16x32_bf16(qf[1][ks], bk, sacc[1][ni], 0, 0, 0);
                }

            if (comp) {
                for (int ni = 0; ni < 4; ni++) {
                    int scol = s0 + ni * 16 + l16;
                    bool ok = (scol >= c0v) & (scol < c1v);
                    for (int g = 0; g < 2; g++)
                        for (int r = 0; r < 4; r++)
                            sacc[g][ni][r] = ok ? exp2f(sacc[g][ni][r]) : 0.0f;
                }
            } else {
                const bool full = (s0 + 80 > iw) && (causal || (s0 < iw + 48));
                int d7b = l16h + (t % 7); if (d7b >= 7) d7b -= 7;
                if (full) {
                    for (int ni = 0; ni < 4; ni++) {
                        int d7 = d7b + 2 * ni; if (d7 >= 7) d7 -= 7;
                        bool line = (0x0B >> d7) & 1;
                        int s = s0 + ni * 16 + l16;
                        for (int g = 0; g < 2; g++)
                            for (int r = 0; r < 4; r++) {
                                int i = irow[g][r];
                                bool ok = causal ? ((s <= i) & (line | (s >= i - 16)))
                                                 : (line | ((s >= i - 16) & (s <= i + 16)));
                                sacc[g][ni][r] = ok ? exp2f(sacc[g][ni][r]) : 0.0f;
                            }
                    }
                } else {
                    for (int ni = 0; ni < 4; ni++) {
                        int d7 = d7b + 2 * ni; if (d7 >= 7) d7 -= 7;
                        bool line = (0x0B >> d7) & 1;
                        for (int g = 0; g < 2; g++)
                            for (int r = 0; r < 4; r++)
                                sacc[g][ni][r] = line ? exp2f(sacc[g][ni][r]) : 0.0f;
                    }
                }
            }

            // P write: linear-64 + XOR row swizzle (chunk = col>>3, ^= row&7)
            for (int g = 0; g < 2; g++)
                for (int ni = 0; ni < 4; ni++)
                    for (int r = 0; r < 4; r++) {
                        int row = g * 16 + quad * 4 + r;
                        Pw[row * 64 + (((ni * 2 + (l16 >> 3)) ^ (row & 7)) * 8) + (l16 & 7)]
                            = f2bf(sacc[g][ni][r]);
                    }

            for (int ks2 = 0; ks2 < 2; ks2++) {
                bf16x8 ap0 = *(const bf16x8*)(Pw + l16 * 64 + ((ks2 * 4 + quad) ^ swz) * 8);
                bf16x8 ap1 = *(const bf16x8*)(Pw + (16 + l16) * 64 + ((ks2 * 4 + quad) ^ swz) * 8);
                lacc[0] = __builtin_amdgcn_mfma_f32_16x16x32_bf16(ap0, vones, lacc[0], 0, 0, 0);
                lacc[1] = __builtin_amdgcn_mfma_f32_16x16x32_bf16(ap1, vones, lacc[1], 0, 0, 0);
                for (int nj = 0; nj < 8; nj++) {
                    bf16x8 bv = *(const bf16x8*)(VsC + (nj * 16 + l16) * 64 + ((ks2 * 4 + quad) ^ swz) * 8);
                    oacc[0][nj] = __builtin_amdgcn_mfma_f32_16x16x32_bf16(ap0, bv, oacc[0][nj], 0, 0, 0);
                    oacc[1][nj] = __builtin_amdgcn_mfma_f32_16x16x32_bf16(ap1, bv, oacc[1][nj], 0, 0, 0);
                }
            }
            cur ^= 1;
        }
    }

    short* Obase = Ocat + (size_t)(b * TT) * HIDDEN + h * HDIM;
    for (int g = 0; g < 2; g++) {
        float inv[4];
        for (int r = 0; r < 4; r++) inv[r] = 1.0f / lacc[g][r];
        for (int nj = 0; nj < 8; nj++)
            for (int r = 0; r < 4; r++)
                Obase[(size_t)irow[g][r] * HIDDEN + nj * 16 + l16] = f2bf(oacc[g][nj][r] * inv[r]);
    }
}

// ---------------- kernel 4: output projection (r6 proven) ----------------
__global__ __launch_bounds__(256) void out_gemm(
    const short* __restrict__ A, const short* __restrict__ Bt, float* __restrict__ out)
{
    __shared__ short Ash[3 * 128 * 32];
    __shared__ short Bsh[3 * 128 * 32];
    const int orig = blockIdx.x;
    const int sblk = (orig & 7) * 56 + (orig >> 3);   // bijective: 448 % 8 == 0
    const int n0 = (sblk % 7) * 128;
    const int m0 = (sblk / 7) * 128;

    const int tid = threadIdx.x;
    const int wave = tid >> 6, lane = tid & 63;
    const int quad = lane >> 4, l16 = lane & 15;
    const int wm = (wave >> 1) * 64, wn = (wave & 1) * 64;

    f32x4 acc[4][4] = {};

    const int r0 = tid >> 2, cc0 = (tid & 3) * 8;
    const int r1 = r0 + 64;
    const short* asrc0 = A + (size_t)(m0 + r0) * HIDDEN + cc0;
    const short* asrc1 = A + (size_t)(m0 + r1) * HIDDEN + cc0;
    const short* bsrc0 = Bt + (size_t)(n0 + r0) * HIDDEN + cc0;
    const short* bsrc1 = Bt + (size_t)(n0 + r1) * HIDDEN + cc0;

    auto STAGE = [&](int kt, int sel) {
        const int ko = kt * 32;
        short* ab = Ash + sel * 4096;
        short* bb = Bsh + sel * 4096;
        gll16(asrc0 + ko, ab + wave * 512);
        gll16(asrc1 + ko, ab + 2048 + wave * 512);
        gll16(bsrc0 + ko, bb + wave * 512);
        gll16(bsrc1 + ko, bb + 2048 + wave * 512);
    };

    STAGE(0, 0);
    const int NT = HIDDEN / 32;         // 28
    for (int t = 0; t < NT; t++) {
        const int sel = t % 3;
        if (t + 1 < NT) {
            STAGE(t + 1, (t + 1) % 3);
            asm volatile("s_waitcnt vmcnt(4)" ::: "memory");
        } else {
            asm volatile("s_waitcnt vmcnt(0)" ::: "memory");
        }
        __builtin_amdgcn_s_barrier();
        __builtin_amdgcn_sched_barrier(0);
        const short* ab = Ash + sel * 4096;
        const short* bb = Bsh + sel * 4096;
        bf16x8 af[4], bfr[4];
        for (int mi = 0; mi < 4; mi++)
            af[mi] = *(const bf16x8*)(ab + (wm + mi * 16 + l16) * 32 + quad * 8);
        for (int ni = 0; ni < 4; ni++)
            bfr[ni] = *(const bf16x8*)(bb + (wn + ni * 16 + l16) * 32 + quad * 8);
        for (int mi = 0; mi < 4; mi++)
            for (int ni = 0; ni < 4; ni++)
                acc[mi][ni] = __builtin_amdgcn_mfma_f32_16x16x32_bf16(af[mi], bfr[ni], acc[mi][ni], 0, 0, 0);
    }

    for (int mi = 0; mi < 4; mi++)
        for (int ni = 0; ni < 4; ni++)
            for (int r = 0; r < 4; r++) {
                int m = m0 + wm + mi * 16 + quad * 4 + r;
                int n = n0 + wn + ni * 16 + l16;
                out[(size_t)m * HIDDEN + n] = acc[mi][ni][r];
            }
}

extern "C" void kernel_launch(void* const* d_in, const int* in_sizes, int n_in,
                              void* d_out, int out_size, void* d_ws, size_t ws_size,
                              hipStream_t stream) {
    (void)in_sizes; (void)n_in; (void)out_size; (void)ws_size;
    const float* x  = (const float*)d_in[0];
    const float* Wq = (const float*)d_in[1];
    const float* Wk = (const float*)d_in[2];
    const float* Wv = (const float*)d_in[3];
    const float* Wo = (const float*)d_in[4];
    const int* iscp = (const int*)d_in[5];
    float* out = (float*)d_out;

    short* xb   = (short*)d_ws;                       // 8192*896 shorts = 14.68 MB
    short* Qb   = xb   + (size_t)MTOT * HIDDEN;       // 7*8192*128 each
    short* Kb   = Qb   + (size_t)HEADS * MTOT * HDIM;
    short* Vtb  = Kb   + (size_t)HEADS * MTOT * HDIM;
    short* Ocat = Vtb  + (size_t)HEADS * MTOT * HDIM; // 8192*896 (aliased with Wt)
    short* Wt   = Ocat;                               // 21*128*896, used only before attn
    short* Wob  = Ocat + (size_t)MTOT * HIDDEN;       // 896*896
    // compacted line-column K/V: 2 x 28*896*128 shorts = 12.85 MB, aliases dead xb
    short* Kc   = xb;
    short* Vc   = Kc + (size_t)28 * SCP * HDIM;

    prep_fused<<<NB_CASTX + NB_CASTWO + NB_TRANS, 256, 0, stream>>>(
        x, Wo, Wq, Wk, Wv, xb, Wob, Wt);
    qkv_gemm<<<21 * (MTOT / 128), 256, 0, stream>>>(xb, Wt, Qb, Kb, Vtb);
    compact_k<<<dim3(28, SCP / 32), 256, 0, stream>>>(Kb, Kc);
    compact_v<<<dim3(28, HDIM), 256, 0, stream>>>(Vtb, Vc);
    fano_attn<<<dim3(TT / 128, BB, HEADS), 256, 0, stream>>>(Qb, Kb, Vtb, Kc, Vc, Ocat, iscp);
    out_gemm<<<(HIDDEN / 128) * (MTOT / 128), 256, 0, stream>>>(Ocat, Wob, out);
}

// Round 8
// 272.998 us; speedup vs baseline: 1.4073x; 1.0243x over previous
//
#include <hip/hip_runtime.h>
#include <hip/hip_bf16.h>

#define HIDDEN 896
#define HEADS 7
#define HDIM 128
#define BB 4
#define TT 2048
#define MTOT (BB*TT)   // 8192

#define SCP 896        // compacted line-column buffer: padded length (>= 879, mult of 64)

typedef short bf16x8 __attribute__((ext_vector_type(8)));
typedef float f32x4 __attribute__((ext_vector_type(4)));

__device__ __forceinline__ short f2bf(float f) {
    union { float f; unsigned u; } v; v.f = f;
    unsigned r = (v.u + 0x7FFF + ((v.u >> 16) & 1)) >> 16;
    return (short)r;
}

// async global->LDS, 16B per lane; lds dst must be wave-uniform base (+lane*16 implicit)
__device__ __forceinline__ void gll16(const short* g, short* l) {
    __builtin_amdgcn_global_load_lds(
        (const __attribute__((address_space(1))) unsigned int*)g,
        (__attribute__((address_space(3))) unsigned int*)l, 16, 0, 0);
}

// line membership: head h attends column s iff bit (s%7) of m_h set, m_h = {h,h+1,h+3} mod 7
__device__ __forceinline__ unsigned linemask(int h) {
    return ((0x0Bu << h) | (0x0Bu >> (7 - h))) & 0x7Fu;
}
// number of line columns with s < X  (X >= 0)
__device__ __forceinline__ int linecnt(unsigned m, int X) {
    return (X / 7) * 3 + __popc(m & ((1u << (X % 7)) - 1u));
}

// ---------------- kernel 1: fused prep (cast x, cast Wo, transpose-cast Wq/Wk/Wv) ----
#define NB_CASTX (MTOT * HIDDEN / 1024)      // 7168
#define NB_CASTWO (HIDDEN * HIDDEN / 1024)   // 784
#define NB_TRANS (28 * 4 * 21)               // 2352
__global__ __launch_bounds__(256) void prep_fused(
    const float* __restrict__ x, const float* __restrict__ Wo,
    const float* __restrict__ Wq, const float* __restrict__ Wk,
    const float* __restrict__ Wv,
    short* __restrict__ xb, short* __restrict__ Wob, short* __restrict__ Wt)
{
    __shared__ float tile[32][33];
    const int bid = blockIdx.x;
    if (bid < NB_CASTX) {
        int base = (bid * 256 + threadIdx.x) * 4;
        float4 v = *(const float4*)(x + base);
        short4 o;
        o.x = f2bf(v.x); o.y = f2bf(v.y); o.z = f2bf(v.z); o.w = f2bf(v.w);
        *(short4*)(xb + base) = o;
    } else if (bid < NB_CASTX + NB_CASTWO) {
        int base = ((bid - NB_CASTX) * 256 + threadIdx.x) * 4;
        float4 v = *(const float4*)(Wo + base);
        short4 o;
        o.x = f2bf(v.x); o.y = f2bf(v.y); o.z = f2bf(v.z); o.w = f2bf(v.w);
        *(short4*)(Wob + base) = o;
    } else {
        int t = bid - NB_CASTX - NB_CASTWO;
        const int z = t / 112;               // 0..20
        const int rem = t % 112;
        const int bx = rem % 28, by = rem / 28;
        const int type = z / 7, head = z % 7;
        const float* src = (type == 0 ? Wq : (type == 1 ? Wk : Wv)) + head * (HIDDEN * HDIM);
        short* dst = Wt + (size_t)z * (HDIM * HIDDEN);
        const int r0 = bx * 32, c0 = by * 32;
        const int tx = threadIdx.x & 31, ty = threadIdx.x >> 5;  // 32 x 8
        for (int i = 0; i < 4; i++)
            tile[ty * 4 + i][tx] = src[(r0 + ty * 4 + i) * HDIM + c0 + tx];
        __syncthreads();
        for (int i = 0; i < 4; i++)
            dst[(c0 + ty * 4 + i) * HIDDEN + r0 + tx] = f2bf(tile[tx][ty * 4 + i]);
    }
}

// ---------------- kernel 2: QKV projection GEMM (r6 proven: XCD swizzle + pipeline) --
__global__ __launch_bounds__(256) void qkv_gemm(
    const short* __restrict__ xb, const short* __restrict__ Wt,
    short* __restrict__ Q, short* __restrict__ Kk, short* __restrict__ Vt)
{
    __shared__ short Ash[3 * 128 * 32];
    __shared__ short Bsh[3 * 128 * 32];
    const int orig = blockIdx.x;
    const int sblk = (orig & 7) * 168 + (orig >> 3);   // bijective: 1344 % 8 == 0
    const int z = sblk % 21;
    const int m0 = (sblk / 21) * 128;
    const int head = z % 7, type = z / 7;
    const short* Wz = Wt + (size_t)z * (HDIM * HIDDEN);

    const int tid = threadIdx.x;
    const int wave = tid >> 6, lane = tid & 63;
    const int quad = lane >> 4, l16 = lane & 15;
    const int wm = (wave >> 1) * 64, wn = (wave & 1) * 64;

    f32x4 acc[4][4] = {};

    const int r0 = tid >> 2, cc0 = (tid & 3) * 8;
    const int r1 = r0 + 64;
    const short* asrc0 = xb + (size_t)(m0 + r0) * HIDDEN + cc0;
    const short* asrc1 = xb + (size_t)(m0 + r1) * HIDDEN + cc0;
    const short* bsrc0 = Wz + (size_t)r0 * HIDDEN + cc0;
    const short* bsrc1 = Wz + (size_t)r1 * HIDDEN + cc0;

    auto STAGE = [&](int kt, int sel) {
        const int ko = kt * 32;
        short* ab = Ash + sel * 4096;
        short* bb = Bsh + sel * 4096;
        gll16(asrc0 + ko, ab + wave * 512);
        gll16(asrc1 + ko, ab + 2048 + wave * 512);
        gll16(bsrc0 + ko, bb + wave * 512);
        gll16(bsrc1 + ko, bb + 2048 + wave * 512);
    };

    STAGE(0, 0);
    const int NT = HIDDEN / 32;         // 28
    for (int t = 0; t < NT; t++) {
        const int sel = t % 3;
        if (t + 1 < NT) {
            STAGE(t + 1, (t + 1) % 3);
            asm volatile("s_waitcnt vmcnt(4)" ::: "memory");
        } else {
            asm volatile("s_waitcnt vmcnt(0)" ::: "memory");
        }
        __builtin_amdgcn_s_barrier();
        __builtin_amdgcn_sched_barrier(0);
        const short* ab = Ash + sel * 4096;
        const short* bb = Bsh + sel * 4096;
        bf16x8 af[4], bfr[4];
        for (int mi = 0; mi < 4; mi++)
            af[mi] = *(const bf16x8*)(ab + (wm + mi * 16 + l16) * 32 + quad * 8);
        for (int ni = 0; ni < 4; ni++)
            bfr[ni] = *(const bf16x8*)(bb + (wn + ni * 16 + l16) * 32 + quad * 8);
        for (int mi = 0; mi < 4; mi++)
            for (int ni = 0; ni < 4; ni++)
                acc[mi][ni] = __builtin_amdgcn_mfma_f32_16x16x32_bf16(af[mi], bfr[ni], acc[mi][ni], 0, 0, 0);
    }

    const size_t base = (size_t)head * (MTOT * HDIM);
    if (type == 0) {
        const float qs = 0.08838834764831845f * 1.4426950408889634f;
        for (int mi = 0; mi < 4; mi++)
            for (int ni = 0; ni < 4; ni++)
                for (int r = 0; r < 4; r++) {
                    int m = m0 + wm + mi * 16 + quad * 4 + r;
                    int n = wn + ni * 16 + l16;
                    Q[base + (size_t)m * HDIM + n] = f2bf(acc[mi][ni][r] * qs);
                }
    } else if (type == 1) {
        for (int mi = 0; mi < 4; mi++)
            for (int ni = 0; ni < 4; ni++)
                for (int r = 0; r < 4; r++) {
                    int m = m0 + wm + mi * 16 + quad * 4 + r;
                    int n = wn + ni * 16 + l16;
                    Kk[base + (size_t)m * HDIM + n] = f2bf(acc[mi][ni][r]);
                }
    } else {
        for (int mi = 0; mi < 4; mi++)
            for (int ni = 0; ni < 4; ni++) {
                int m = m0 + wm + mi * 16 + quad * 4;
                int bb2 = m >> 11, t = m & 2047;
                int n = wn + ni * 16 + l16;
                short4 o;
                o.x = f2bf(acc[mi][ni][0]); o.y = f2bf(acc[mi][ni][1]);
                o.z = f2bf(acc[mi][ni][2]); o.w = f2bf(acc[mi][ni][3]);
                *(short4*)(Vt + base + (size_t)bb2 * (HDIM * TT) + (size_t)n * TT + t) = o;
            }
    }
}

// ---------------- kernel 2.5a: compact K to line-columns (ascending s) ----------------
__global__ __launch_bounds__(256) void compact_k(const short* __restrict__ K,
                                                 short* __restrict__ Kc)
{
    const int hb = blockIdx.x, h = hb >> 2, b = hb & 3;
    const unsigned m = linemask(h);
    const int c_tot = 876 + __popc(m & 0xFu);
    const int o0 = __ffs(m) - 1;
    const unsigned m1 = m & (m - 1);
    const int o1 = __ffs(m1) - 1;
    const unsigned m2 = m1 & (m1 - 1);
    const int o2 = __ffs(m2) - 1;
    const int r = blockIdx.y * 32 + (threadIdx.x >> 3);
    const int c = (threadIdx.x & 7) * 16;
    short* dst = Kc + ((size_t)hb * SCP + r) * HDIM + c;
    if (r < c_tot) {
        int g = r / 3, id = r - g * 3;
        int s = g * 7 + (id == 0 ? o0 : (id == 1 ? o1 : o2));
        const short* src = K + (size_t)(h * MTOT + b * TT + s) * HDIM + c;
        *(bf16x8*)dst = *(const bf16x8*)src;
        *(bf16x8*)(dst + 8) = *(const bf16x8*)(src + 8);
    } else {
        bf16x8 zz = {};
        *(bf16x8*)dst = zz;
        *(bf16x8*)(dst + 8) = zz;
    }
}

// ---------------- kernel 2.5b: compact V^T to line-columns ----------------
__global__ __launch_bounds__(256) void compact_v(const short* __restrict__ Vt,
                                                 short* __restrict__ Vc)
{
    const int hb = blockIdx.x, h = hb >> 2, b = hb & 3;
    const int d = blockIdx.y;
    const unsigned m = linemask(h);
    const int c_tot = 876 + __popc(m & 0xFu);
    const int o0 = __ffs(m) - 1;
    const unsigned m1 = m & (m - 1);
    const int o1 = __ffs(m1) - 1;
    const unsigned m2 = m1 & (m1 - 1);
    const int o2 = __ffs(m2) - 1;
    const short* src = Vt + (size_t)h * MTOT * HDIM + (size_t)b * HDIM * TT + (size_t)d * TT;
    short* dst = Vc + ((size_t)hb * HDIM + d) * SCP;
    for (int sp = threadIdx.x * 4; sp < SCP; sp += 1024) {
        short4 o;
        short* po = (short*)&o;
        for (int j = 0; j < 4; j++) {
            int spp = sp + j;
            short v = 0;
            if (spp < c_tot) {
                int g = spp / 3, id = spp - g * 3;
                int s = g * 7 + (id == 0 ? o0 : (id == 1 ? o1 : o2));
                v = src[s];
            }
            po[j] = v;
        }
        *(short4*)(dst + sp) = o;
    }
}

// ---------------- kernel 3: fano flash attention v15 (intra-block split-S) ----------
// 512 threads = 2 wave-groups of 4. Group g processes steps u=2j+g of the flattened
// A/B/C step list with its OWN double-buffered K/V LDS tiles; partials are linearly
// additive (exp2-direct, no online max), so group 1 dumps (oacc,lacc) f32 into the
// then-dead K/V LDS area and group 0 merges+normalizes. Halves the serial step count
// of the straggler blocks (the measured wall). LDS: 2grp*2buf*32KB + 8*4KB P = 160 KiB.
__global__ __launch_bounds__(512) void fano_attn(
    const short* __restrict__ Q, const short* __restrict__ K, const short* __restrict__ Vt,
    const short* __restrict__ Kc, const short* __restrict__ Vc,
    short* __restrict__ Ocat, const int* __restrict__ iscp)
{
    __shared__ short L[81920];   // 160 KiB exactly

    const int causal = *iscp;
    const int qt = causal ? (TT / 128 - 1 - (int)blockIdx.x) : (int)blockIdx.x;
    const int q0 = qt * 128;
    const int b = blockIdx.y, h = blockIdx.z;
    const int hb = h * 4 + b;
    const int tid = threadIdx.x;
    const int wave = tid >> 6, grp = wave >> 2, wg = wave & 3, lane = tid & 63;
    const int quad = lane >> 4, l16 = lane & 15;
    const int iw = q0 + wg * 32;
    const int swz = l16 & 7;

    const short* Qb = Q + (size_t)(h * MTOT + b * TT + q0) * HDIM;
    const short* Kb = K + (size_t)(h * MTOT + b * TT) * HDIM;
    const short* Vb = Vt + (size_t)h * MTOT * HDIM + (size_t)b * HDIM * TT;
    const short* Kcb = Kc + (size_t)hb * SCP * HDIM;
    const short* Vcb = Vc + (size_t)hb * HDIM * SCP;

    // stage-source precompute: linear LDS chunk c = (wg*4+i)*64 + lane; src chunk ^= row&7
    int krowS[4], kccS[4], vrowS[4], vccS[4];
    for (int i = 0; i < 4; i++) {
        int c = (wg * 4 + i) * 64 + lane;
        krowS[i] = c >> 4; kccS[i] = ((c & 15) ^ (krowS[i] & 7)) * 8;
        vrowS[i] = c >> 3; vccS[i] = ((c & 7) ^ (vrowS[i] & 7)) * 8;
    }

    auto STAGE = [&](const short* Kp, const short* Vp, int vstr, int s0, int c) {
        short* kb = L + (grp * 2 + c) * 16384;
        short* vb = kb + 8192;
        for (int i = 0; i < 4; i++) {
            gll16(Kp + (size_t)(s0 + krowS[i]) * HDIM + kccS[i], kb + (wg * 4 + i) * 512);
            gll16(Vp + (size_t)vrowS[i] * vstr + s0 + vccS[i], vb + (wg * 4 + i) * 512);
        }
    };

    bf16x8 qf[2][4];
    for (int g = 0; g < 2; g++)
        for (int ks = 0; ks < 4; ks++)
            qf[g][ks] = *(const bf16x8*)(Qb + (size_t)(wg * 32 + g * 16 + l16) * HDIM + ks * 32 + quad * 8);

    f32x4 oacc[2][8] = {};
    f32x4 lacc[2] = {};
    int irow[2][4];
    for (int g = 0; g < 2; g++)
        for (int r = 0; r < 4; r++)
            irow[g][r] = q0 + wg * 32 + g * 16 + quad * 4 + r;

    const bf16x8 vones = {0x3F80, 0x3F80, 0x3F80, 0x3F80, 0x3F80, 0x3F80, 0x3F80, 0x3F80};

    const unsigned m_h = linemask(h);
    const int c_tot = 876 + __popc(m_h & 0xFu);
    const int sB0 = (causal && q0 >= 64) ? (q0 - 64) : 0;
    const int sB1 = causal ? (q0 + 128) : (q0 + 192 < TT ? q0 + 192 : TT);
    const int cA = linecnt(m_h, sB0);
    const int cC0 = causal ? c_tot : linecnt(m_h, sB1);
    const int l16h = (l16 - h + 7) % 7;

    // phase list (only nonempty phases)
    const short* Kpa[3]; const short* Vpa[3];
    int vstra[3], ta0[3], ta1[3], cv0a[3], cv1a[3], cmpa[3];
    int np = 0;
    {
        int t1A = (cA + 63) >> 6;
        if (t1A > 0) { Kpa[np] = Kcb; Vpa[np] = Vcb; vstra[np] = SCP; ta0[np] = 0; ta1[np] = t1A; cv0a[np] = 0; cv1a[np] = cA; cmpa[np] = 1; np++; }
    }
    {
        int t0B = sB0 >> 6, t1B = sB1 >> 6;
        if (t1B > t0B) { Kpa[np] = Kb; Vpa[np] = Vb; vstra[np] = TT; ta0[np] = t0B; ta1[np] = t1B; cv0a[np] = 0; cv1a[np] = 0; cmpa[np] = 0; np++; }
    }
    if (!causal) {
        int t0C = cC0 >> 6, t1C = (c_tot + 63) >> 6;
        if (t1C > t0C) { Kpa[np] = Kcb; Vpa[np] = Vcb; vstra[np] = SCP; ta0[np] = t0C; ta1[np] = t1C; cv0a[np] = cC0; cv1a[np] = c_tot; cmpa[np] = 1; np++; }
    }
    int ns = 0;
    for (int i = 0; i < np; i++) ns += ta1[i] - ta0[i];

    auto stepOf = [&](int u, int& pi, int& t) {
        int acc = 0;
        for (int i = 0; i < np; i++) {
            int len = ta1[i] - ta0[i];
            if (u < acc + len) { pi = i; t = ta0[i] + (u - acc); return; }
            acc += len;
        }
        pi = 0; t = ta0[0];
    };

    short* Pw = L + 65536 + wave * 2048;
    int cur = 0;

    // prologue: group's first step (u = grp; ns >= 2 always)
    {
        int pi, t; stepOf(grp, pi, t);
        STAGE(Kpa[pi], Vpa[pi], vstra[pi], t * 64, 0);
    }

    const int nrounds = (ns + 1) >> 1;
    for (int j = 0; j < nrounds; j++) {
        const int u = 2 * j + grp;
        const bool act = (u < ns);
        if (act) asm volatile("s_waitcnt vmcnt(0)" ::: "memory");  // my tile-u DMAs done
        __builtin_amdgcn_s_barrier();
        __builtin_amdgcn_sched_barrier(0);
        const int un = u + 2;
        if (un < ns) {
            int pn, tn; stepOf(un, pn, tn);
            STAGE(Kpa[pn], Vpa[pn], vstra[pn], tn * 64, cur ^ 1);
        }
        if (act) {
            int pi, t; stepOf(u, pi, t);
            const int comp = cmpa[pi], c0v = cv0a[pi], c1v = cv1a[pi];
            const short* KsC = L + (grp * 2 + cur) * 16384;
            const short* VsC = KsC + 8192;
            const int s0 = t * 64;

            f32x4 sacc[2][4] = {};
            for (int ni = 0; ni < 4; ni++)
                for (int ks = 0; ks < 4; ks++) {
                    bf16x8 bk = *(const bf16x8*)(KsC + (ni * 16 + l16) * 128 + ((ks * 4 + quad) ^ swz) * 8);
                    sacc[0][ni] = __builtin_amdgcn_mfma_f32_16x16x32_bf16(qf[0][ks], bk, sacc[0][ni], 0, 0, 0);
                    sacc[1][ni] = __builtin_amdgcn_mfma_f32_16x16x32_bf16(qf[1][ks], bk, sacc[1][ni], 0, 0, 0);
                }

            if (comp) {
                for (int ni = 0; ni < 4; ni++) {
                    int scol = s0 + ni * 16 + l16;
                    bool ok = (scol >= c0v) & (scol < c1v);
                    for (int g = 0; g < 2; g++)
                        for (int r = 0; r < 4; r++)
                            sacc[g][ni][r] = ok ? exp2f(sacc[g][ni][r]) : 0.0f;
                }
            } else {
                const bool full = (s0 + 80 > iw) && (causal || (s0 < iw + 48));
                int d7b = l16h + (t % 7); if (d7b >= 7) d7b -= 7;
                if (full) {
                    for (int ni = 0; ni < 4; ni++) {
                        int d7 = d7b + 2 * ni; if (d7 >= 7) d7 -= 7;
                        bool line = (0x0B >> d7) & 1;
                        int s = s0 + ni * 16 + l16;
                        for (int g = 0; g < 2; g++)
                            for (int r = 0; r < 4; r++) {
                                int i = irow[g][r];
                                bool ok = causal ? ((s <= i) & (line | (s >= i - 16)))
                                                 : (line | ((s >= i - 16) & (s <= i + 16)));
                                sacc[g][ni][r] = ok ? exp2f(sacc[g][ni][r]) : 0.0f;
                            }
                    }
                } else {
                    for (int ni = 0; ni < 4; ni++) {
                        int d7 = d7b + 2 * ni; if (d7 >= 7) d7 -= 7;
                        bool line = (0x0B >> d7) & 1;
                        for (int g = 0; g < 2; g++)
                            for (int r = 0; r < 4; r++)
                                sacc[g][ni][r] = line ? exp2f(sacc[g][ni][r]) : 0.0f;
                    }
                }
            }

            // P write: linear-64 + XOR row swizzle
            for (int g = 0; g < 2; g++)
                for (int ni = 0; ni < 4; ni++)
                    for (int r = 0; r < 4; r++) {
                        int row = g * 16 + quad * 4 + r;
                        Pw[row * 64 + (((ni * 2 + (l16 >> 3)) ^ (row & 7)) * 8) + (l16 & 7)]
                            = f2bf(sacc[g][ni][r]);
                    }

            for (int ks2 = 0; ks2 < 2; ks2++) {
                bf16x8 ap0 = *(const bf16x8*)(Pw + l16 * 64 + ((ks2 * 4 + quad) ^ swz) * 8);
                bf16x8 ap1 = *(const bf16x8*)(Pw + (16 + l16) * 64 + ((ks2 * 4 + quad) ^ swz) * 8);
                lacc[0] = __builtin_amdgcn_mfma_f32_16x16x32_bf16(ap0, vones, lacc[0], 0, 0, 0);
                lacc[1] = __builtin_amdgcn_mfma_f32_16x16x32_bf16(ap1, vones, lacc[1], 0, 0, 0);
                for (int nj = 0; nj < 8; nj++) {
                    bf16x8 bv = *(const bf16x8*)(VsC + (nj * 16 + l16) * 64 + ((ks2 * 4 + quad) ^ swz) * 8);
                    oacc[0][nj] = __builtin_amdgcn_mfma_f32_16x16x32_bf16(ap0, bv, oacc[0][nj], 0, 0, 0);
                    oacc[1][nj] = __builtin_amdgcn_mfma_f32_16x16x32_bf16(ap1, bv, oacc[1][nj], 0, 0, 0);
                }
            }
        }
        cur ^= 1;
    }

    // ---- merge group partials (linear: no online max) ----
    __syncthreads();                       // all compute done; K/V LDS area dead
    float* Lf = (float*)L;
    if (grp == 1) {
        float* od = Lf + wg * 4096;
        for (int g = 0; g < 2; g++)
            for (int nj = 0; nj < 8; nj++)
                *(f32x4*)(od + ((g * 8 + nj) * 64 + lane) * 4) = oacc[g][nj];
        float* ld = Lf + 16384 + wg * 512;
        for (int g = 0; g < 2; g++)
            *(f32x4*)(ld + (g * 64 + lane) * 4) = lacc[g];
    }
    __syncthreads();
    if (grp == 0) {
        float* od = Lf + wg * 4096;
        float* ld = Lf + 16384 + wg * 512;
        for (int g = 0; g < 2; g++) {
            lacc[g] += *(const f32x4*)(ld + (g * 64 + lane) * 4);
            for (int nj = 0; nj < 8; nj++)
                oacc[g][nj] += *(const f32x4*)(od + ((g * 8 + nj) * 64 + lane) * 4);
        }
        short* Obase = Ocat + (size_t)(b * TT) * HIDDEN + h * HDIM;
        for (int g = 0; g < 2; g++) {
            float inv[4];
            for (int r = 0; r < 4; r++) inv[r] = 1.0f / lacc[g][r];
            for (int nj = 0; nj < 8; nj++)
                for (int r = 0; r < 4; r++)
                    Obase[(size_t)irow[g][r] * HIDDEN + nj * 16 + l16] = f2bf(oacc[g][nj][r] * inv[r]);
        }
    }
}

// ---------------- kernel 4: output projection (r6 proven) ----------------
__global__ __launch_bounds__(256) void out_gemm(
    const short* __restrict__ A, const short* __restrict__ Bt, float* __restrict__ out)
{
    __shared__ short Ash[3 * 128 * 32];
    __shared__ short Bsh[3 * 128 * 32];
    const int orig = blockIdx.x;
    const int sblk = (orig & 7) * 56 + (orig >> 3);   // bijective: 448 % 8 == 0
    const int n0 = (sblk % 7) * 128;
    const int m0 = (sblk / 7) * 128;

    const int tid = threadIdx.x;
    const int wave = tid >> 6, lane = tid & 63;
    const int quad = lane >> 4, l16 = lane & 15;
    const int wm = (wave >> 1) * 64, wn = (wave & 1) * 64;

    f32x4 acc[4][4] = {};

    const int r0 = tid >> 2, cc0 = (tid & 3) * 8;
    const int r1 = r0 + 64;
    const short* asrc0 = A + (size_t)(m0 + r0) * HIDDEN + cc0;
    const short* asrc1 = A + (size_t)(m0 + r1) * HIDDEN + cc0;
    const short* bsrc0 = Bt + (size_t)(n0 + r0) * HIDDEN + cc0;
    const short* bsrc1 = Bt + (size_t)(n0 + r1) * HIDDEN + cc0;

    auto STAGE = [&](int kt, int sel) {
        const int ko = kt * 32;
        short* ab = Ash + sel * 4096;
        short* bb = Bsh + sel * 4096;
        gll16(asrc0 + ko, ab + wave * 512);
        gll16(asrc1 + ko, ab + 2048 + wave * 512);
        gll16(bsrc0 + ko, bb + wave * 512);
        gll16(bsrc1 + ko, bb + 2048 + wave * 512);
    };

    STAGE(0, 0);
    const int NT = HIDDEN / 32;         // 28
    for (int t = 0; t < NT; t++) {
        const int sel = t % 3;
        if (t + 1 < NT) {
            STAGE(t + 1, (t + 1) % 3);
            asm volatile("s_waitcnt vmcnt(4)" ::: "memory");
        } else {
            asm volatile("s_waitcnt vmcnt(0)" ::: "memory");
        }
        __builtin_amdgcn_s_barrier();
        __builtin_amdgcn_sched_barrier(0);
        const short* ab = Ash + sel * 4096;
        const short* bb = Bsh + sel * 4096;
        bf16x8 af[4], bfr[4];
        for (int mi = 0; mi < 4; mi++)
            af[mi] = *(const bf16x8*)(ab + (wm + mi * 16 + l16) * 32 + quad * 8);
        for (int ni = 0; ni < 4; ni++)
            bfr[ni] = *(const bf16x8*)(bb + (wn + ni * 16 + l16) * 32 + quad * 8);
        for (int mi = 0; mi < 4; mi++)
            for (int ni = 0; ni < 4; ni++)
                acc[mi][ni] = __builtin_amdgcn_mfma_f32_16x16x32_bf16(af[mi], bfr[ni], acc[mi][ni], 0, 0, 0);
    }

    for (int mi = 0; mi < 4; mi++)
        for (int ni = 0; ni < 4; ni++)
            for (int r = 0; r < 4; r++) {
                int m = m0 + wm + mi * 16 + quad * 4 + r;
                int n = n0 + wn + ni * 16 + l16;
                out[(size_t)m * HIDDEN + n] = acc[mi][ni][r];
            }
}

extern "C" void kernel_launch(void* const* d_in, const int* in_sizes, int n_in,
                              void* d_out, int out_size, void* d_ws, size_t ws_size,
                              hipStream_t stream) {
    (void)in_sizes; (void)n_in; (void)out_size; (void)ws_size;
    const float* x  = (const float*)d_in[0];
    const float* Wq = (const float*)d_in[1];
    const float* Wk = (const float*)d_in[2];
    const float* Wv = (const float*)d_in[3];
    const float* Wo = (const float*)d_in[4];
    const int* iscp = (const int*)d_in[5];
    float* out = (float*)d_out;

    short* xb   = (short*)d_ws;                       // 8192*896 shorts = 14.68 MB
    short* Qb   = xb   + (size_t)MTOT * HIDDEN;       // 7*8192*128 each
    short* Kb   = Qb   + (size_t)HEADS * MTOT * HDIM;
    short* Vtb  = Kb   + (size_t)HEADS * MTOT * HDIM;
    short* Ocat = Vtb  + (size_t)HEADS * MTOT * HDIM; // 8192*896 (aliased with Wt)
    short* Wt   = Ocat;                               // 21*128*896, used only before attn
    short* Wob  = Ocat + (size_t)MTOT * HIDDEN;       // 896*896
    // compacted line-column K/V: 2 x 28*896*128 shorts = 12.85 MB, aliases dead xb
    short* Kc   = xb;
    short* Vc   = Kc + (size_t)28 * SCP * HDIM;

    prep_fused<<<NB_CASTX + NB_CASTWO + NB_TRANS, 256, 0, stream>>>(
        x, Wo, Wq, Wk, Wv, xb, Wob, Wt);
    qkv_gemm<<<21 * (MTOT / 128), 256, 0, stream>>>(xb, Wt, Qb, Kb, Vtb);
    compact_k<<<dim3(28, SCP / 32), 256, 0, stream>>>(Kb, Kc);
    compact_v<<<dim3(28, HDIM), 256, 0, stream>>>(Vtb, Vc);
    fano_attn<<<dim3(TT / 128, BB, HEADS), 512, 0, stream>>>(Qb, Kb, Vtb, Kc, Vc, Ocat, iscp);
    out_gemm<<<(HIDDEN / 128) * (MTOT / 128), 256, 0, stream>>>(Ocat, Wob, out);
}